// Round 6
// baseline (2405.478 us; speedup 1.0000x reference)
//
#include <hip/hip_runtime.h>
#include <hip/hip_bf16.h>
#include <cstdint>

#define B_ 512
#define T_ 48
#define N_ 62
#define F_ 5
#define E_ 496
#define H_ 512
#define NF_ 310      // N*F
#define SEQP 320     // padded seq row (310 -> 320)
#define KPAD 832     // 320 + 512
#define G4 2048      // 4*H
#define EPS_ 1e-5f
#define TC 12        // t-steps per cheb block (4 chunks)
#define LSTR 72      // LDS row stride in shorts (16B-aligned, conflict-light)

typedef __attribute__((ext_vector_type(8))) short short8;
typedef __attribute__((ext_vector_type(4))) short s16x4;
typedef __attribute__((ext_vector_type(4))) float f32x4;

__device__ __forceinline__ float sigm(float x)  { return 1.f / (1.f + __expf(-x)); }
__device__ __forceinline__ float tanhf_(float x){ return 2.f / (1.f + __expf(-2.f*x)) - 1.f; }

__device__ __forceinline__ short f2b(float v) {   // f32 -> bf16 bits, RN-even
  unsigned int u = __builtin_bit_cast(unsigned int, v);
  unsigned int r = (u + 0x7fffu + ((u >> 16) & 1u)) >> 16;
  return (short)r;
}
__device__ __forceinline__ float b2f(short s) {   // bf16 bits -> f32
  unsigned int u = ((unsigned int)(unsigned short)s) << 16;
  return __builtin_bit_cast(float, u);
}

// ============ ChebConv K=3 via MFMA + BN partial stats; block = (graph, 12-t chunk) ============
__global__ __launch_bounds__(512) void k_cheb(
    const float* __restrict__ x, const int* __restrict__ esrc, const int* __restrict__ edst,
    const float* __restrict__ ew, const float* __restrict__ Wc, const float* __restrict__ bc,
    float* __restrict__ cheb, float* __restrict__ bps, float* __restrict__ bpq)
{
  __shared__ __align__(16) short SH[4*64*LSTR];   // Lb | Xt | T1t | T2t
  __shared__ float dinv[N_];
  short* Lb  = SH;                 // Lhat bf16 [n][m], 64x64 zero-padded
  short* Xt  = SH + 64*LSTR;       // X^T  bf16 [c=tl*5+f][m=n], 60 rows used
  short* T1t = SH + 2*64*LSTR;     // T1^T
  short* T2t = SH + 3*64*LSTR;     // T2^T
  float* Af  = (float*)T1t;        // f32 A 62x62 = 15376 B overlays T1t+T2t (18432 B)

  const int tid = threadIdx.x;
  const int b = blockIdx.x;
  const int t0 = blockIdx.y * TC;

  for (int i = tid; i < 2*64*LSTR; i += 512) SH[i] = 0;      // zero Lb + Xt
  for (int i = tid; i < N_*N_;     i += 512) Af[i] = 0.f;
  __syncthreads();

  // build A + load X^T
  for (int e = tid; e < E_; e += 512)
    atomicAdd(&Af[edst[b*E_ + e]*N_ + esrc[b*E_ + e]], ew[b*E_ + e]);
  for (int i = tid; i < TC*NF_; i += 512) {
    int tl = i / NF_, nf = i - tl*NF_;
    float v = x[((size_t)b*T_ + t0 + tl)*NF_ + nf];
    int n = nf / F_, f = nf - n*F_;
    Xt[(tl*F_ + f)*LSTR + n] = f2b(v);
  }
  __syncthreads();

  if (tid < N_) {
    float s = 0.f;
    for (int m = 0; m < N_; ++m) s += Af[tid*N_ + m];
    dinv[tid] = (s > 0.f) ? rsqrtf(s) : 0.f;
  }
  __syncthreads();
  for (int i = tid; i < N_*N_; i += 512) {
    int n = i / N_, m = i - n*N_;
    Lb[n*LSTR + m] = f2b(-dinv[n] * Af[i] * dinv[m]);
  }
  __syncthreads();                                // Af dead; T1t/T2t writable

  const int w = tid >> 6, lane = tid & 63, l16 = lane & 15, lhi = lane >> 4;
  const int mt = w >> 1;                          // M-tile (n) 0..3
  const int nt = (w & 1) * 2;                     // base N-tile (c): {0,1} or {2,3}

  // ---- T1 = Lhat @ X ----
  {
    f32x4 acc0 = {0.f,0.f,0.f,0.f}, acc1 = acc0;
    #pragma unroll
    for (int kc = 0; kc < 2; ++kc) {
      short8 a  = *(const short8*)(Lb + (mt*16 + l16)*LSTR + kc*32 + lhi*8);
      short8 b0 = *(const short8*)(Xt + ((nt  )*16 + l16)*LSTR + kc*32 + lhi*8);
      short8 b1 = *(const short8*)(Xt + ((nt+1)*16 + l16)*LSTR + kc*32 + lhi*8);
      acc0 = __builtin_amdgcn_mfma_f32_16x16x32_bf16(a, b0, acc0, 0, 0, 0);
      acc1 = __builtin_amdgcn_mfma_f32_16x16x32_bf16(a, b1, acc1, 0, 0, 0);
    }
    #pragma unroll
    for (int i = 0; i < 2; ++i) {
      f32x4 acc = i ? acc1 : acc0;
      int c = (nt+i)*16 + l16, n = mt*16 + lhi*4;
      s16x4 pk;
      #pragma unroll
      for (int r = 0; r < 4; ++r) pk[r] = f2b(acc[r]);
      *(s16x4*)(T1t + c*LSTR + n) = pk;
    }
  }
  __syncthreads();

  // ---- T2 = 2*Lhat@T1 - X ----
  {
    f32x4 acc0 = {0.f,0.f,0.f,0.f}, acc1 = acc0;
    #pragma unroll
    for (int kc = 0; kc < 2; ++kc) {
      short8 a  = *(const short8*)(Lb + (mt*16 + l16)*LSTR + kc*32 + lhi*8);
      short8 b0 = *(const short8*)(T1t + ((nt  )*16 + l16)*LSTR + kc*32 + lhi*8);
      short8 b1 = *(const short8*)(T1t + ((nt+1)*16 + l16)*LSTR + kc*32 + lhi*8);
      acc0 = __builtin_amdgcn_mfma_f32_16x16x32_bf16(a, b0, acc0, 0, 0, 0);
      acc1 = __builtin_amdgcn_mfma_f32_16x16x32_bf16(a, b1, acc1, 0, 0, 0);
    }
    #pragma unroll
    for (int i = 0; i < 2; ++i) {
      f32x4 acc = i ? acc1 : acc0;
      int c = (nt+i)*16 + l16, n = mt*16 + lhi*4;
      s16x4 xv = *(const s16x4*)(Xt + c*LSTR + n);
      s16x4 pk;
      #pragma unroll
      for (int r = 0; r < 4; ++r) pk[r] = f2b(2.f*acc[r] - b2f(xv[r]));
      *(s16x4*)(T2t + c*LSTR + n) = pk;
    }
  }
  __syncthreads();

  // ---- out[t][n][g] = bc + sum_f X*W0 + T1*W1 + T2*W2 ; + BN partials over n ----
  const int pair = tid >> 2, q = tid & 3;
  if (pair < TC*F_) {
    const int tl = pair / F_, g = pair - (pair/F_)*F_;
    const int t = t0 + tl;
    float w0[5], w1[5], w2[5];
    #pragma unroll
    for (int ff = 0; ff < 5; ++ff) {
      w0[ff] = Wc[t*75 +      ff*5 + g];
      w1[ff] = Wc[t*75 + 25 + ff*5 + g];
      w2[ff] = Wc[t*75 + 50 + ff*5 + g];
    }
    const float bias = bc[t*F_ + g];
    float ss = 0.f, qq = 0.f;
    float* chout = cheb + ((size_t)t*B_ + b)*NF_;
    #pragma unroll
    for (int grp = 0; grp < 4; ++grp) {
      int n4 = grp*16 + q*4;
      float o[4] = {bias, bias, bias, bias};
      #pragma unroll
      for (int ff = 0; ff < 5; ++ff) {
        int c = tl*F_ + ff;
        s16x4 xv = *(const s16x4*)(Xt  + c*LSTR + n4);
        s16x4 v1 = *(const s16x4*)(T1t + c*LSTR + n4);
        s16x4 v2 = *(const s16x4*)(T2t + c*LSTR + n4);
        #pragma unroll
        for (int i = 0; i < 4; ++i)
          o[i] += b2f(xv[i])*w0[ff] + b2f(v1[i])*w1[ff] + b2f(v2[i])*w2[ff];
      }
      #pragma unroll
      for (int i = 0; i < 4; ++i) {
        int n = n4 + i;
        if (n < N_) { chout[n*F_ + g] = o[i]; ss += o[i]; qq += o[i]*o[i]; }
      }
    }
    ss += __shfl_down(ss, 2, 4); ss += __shfl_down(ss, 1, 4);
    qq += __shfl_down(qq, 2, 4); qq += __shfl_down(qq, 1, 4);
    if (q == 0) { bps[(t*F_ + g)*B_ + b] = ss; bpq[(t*F_ + g)*B_ + b] = qq; }
  }
}

// ============ finalize BN scale/shift per (t,f) ============
__global__ __launch_bounds__(64) void k_bnfin(
    const float* __restrict__ bps, const float* __restrict__ bpq,
    const float* __restrict__ bng, const float* __restrict__ bnb,
    float* __restrict__ alpha, float* __restrict__ bet)
{
  const int tf = blockIdx.x;
  const int lane = threadIdx.x;
  float s = 0.f, q = 0.f;
  for (int i = lane; i < B_; i += 64) { s += bps[tf*B_ + i]; q += bpq[tf*B_ + i]; }
  #pragma unroll
  for (int off = 32; off; off >>= 1) { s += __shfl_down(s, off); q += __shfl_down(q, off); }
  if (lane == 0) {
    const float cnt = (float)(B_*N_);
    float mu = s / cnt;
    float var = q / cnt - mu*mu;
    float al = bng[tf] * rsqrtf(var + EPS_);
    alpha[tf] = al;
    bet[tf] = bnb[tf] - mu*al;
  }
}

// ============ BN apply + pack to bf16 padded sequence [t][b][320] ============
__global__ __launch_bounds__(256) void k_seq(
    const float* __restrict__ cheb, const float* __restrict__ alpha, const float* __restrict__ bet,
    __hip_bfloat16* __restrict__ seqb)
{
  int idx = blockIdx.x*256 + threadIdx.x;     // T*B*320
  int k = idx % SEQP;
  int tb = idx / SEQP;                        // t*B + b
  float v = 0.f;
  if (k < NF_) {
    int t = tb / B_;
    int tf = t*F_ + (k % F_);
    v = cheb[(size_t)tb*NF_ + k] * alpha[tf] + bet[tf];
  }
  seqb[idx] = __float2bfloat16(v);
}

// ============ weight prep: gate-interleaved rows j' = jh*4 + gate; K = [seq|pad|h] ============
__global__ __launch_bounds__(256) void k_prep(
    const float* __restrict__ Wih, const float* __restrict__ Whh,
    const float* __restrict__ bih, const float* __restrict__ bhh,
    __hip_bfloat16* __restrict__ Wcat, float* __restrict__ biasr)
{
  const int jp = blockIdx.x;                  // 0..2047
  const int g = jp & 3, jh = jp >> 2;
  const int jo = g*H_ + jh;
  for (int k = threadIdx.x; k < KPAD; k += 256) {
    float v = 0.f;
    if (k < NF_) v = Wih[(size_t)jo*NF_ + k];
    else if (k >= SEQP) v = Whh[(size_t)jo*H_ + (k - SEQP)];
    Wcat[(size_t)jp*KPAD + k] = __float2bfloat16(v);
  }
  if (threadIdx.x == 0) biasr[jp] = bih[jo] + bhh[jo];
}

// ============ persistent LSTM: all 48 steps in one launch ============
// 256 blocks (1/CU), 256 thr = 4 waves. Block (bt=bid&7, jt=bid>>3) owns
// a 64(b) x 64(j') tile for the whole sequence. bt-groups of 32 blocks are
// independent (group only consumes h-rows it produces); agent-scope atomic
// barrier per group per step. bt = bid%8 pins a group to one XCD (heuristic;
// correctness holds via agent-scope ops regardless). c stays in registers.
__global__ __launch_bounds__(256) void k_lstm(
    const __hip_bfloat16* __restrict__ seqb,   // (T, B, 320) bf16
    const __hip_bfloat16* __restrict__ Wcat,   // (2048, 832) gate-interleaved
    const float* __restrict__ biasr,           // (2048)
    __hip_bfloat16* __restrict__ h0,           // (B, 512) ping
    __hip_bfloat16* __restrict__ h1,           // (B, 512) pong
    float* __restrict__ y,                     // (B, T, 512)
    unsigned int* __restrict__ bar)            // (8) zeroed
{
  const int tid = threadIdx.x;
  const int bid = blockIdx.x;
  const int bt = bid & 7, jt = bid >> 3;
  const int b0 = bt*64, j0 = jt*64;
  const int w = tid >> 6, lane = tid & 63, l16 = lane & 15, lhi = lane >> 4;
  const int mt0 = (w >> 1) * 2;                // wave covers mt0, mt0+1
  const int nt0 = (w & 1) * 2;                 // and nt0, nt0+1

  __shared__ float gl[64][68];

  // epilogue mapping: thread -> (erow = tid>>2, jl = (tid&3)+{0,4,8,12})
  const int erow = tid >> 2, ej = tid & 3;
  float c0 = 0.f, c1 = 0.f, c2 = 0.f, c3 = 0.f;
  f32x4 bia0 = *(const f32x4*)(biasr + j0 + (ej     )*4);
  f32x4 bia1 = *(const f32x4*)(biasr + j0 + (ej +  4)*4);
  f32x4 bia2 = *(const f32x4*)(biasr + j0 + (ej +  8)*4);
  f32x4 bia3 = *(const f32x4*)(biasr + j0 + (ej + 12)*4);

  const short* sw = (const short*)Wcat;
  const short* bp0 = sw + (size_t)(j0 + (nt0  )*16 + l16)*KPAD + lhi*8;
  const short* bp1 = sw + (size_t)(j0 + (nt0+1)*16 + l16)*KPAD + lhi*8;

  for (int t = 0; t < T_; ++t) {
    const short* hi_ = (const short*)((t & 1) ? h1 : h0);
    short*       ho_ = (short*)      ((t & 1) ? h0 : h1);
    const short* sa = (const short*)seqb + (size_t)t*B_*SEQP;
    const short* ap0 = sa + (size_t)(b0 + (mt0  )*16 + l16)*SEQP + lhi*8;
    const short* ap1 = sa + (size_t)(b0 + (mt0+1)*16 + l16)*SEQP + lhi*8;
    const short* hp0 = hi_ + (size_t)(b0 + (mt0  )*16 + l16)*H_ + lhi*8;
    const short* hp1 = hi_ + (size_t)(b0 + (mt0+1)*16 + l16)*H_ + lhi*8;

    f32x4 a00 = {0.f,0.f,0.f,0.f}, a01 = a00, a10 = a00, a11 = a00;
    #pragma unroll
    for (int kc = 0; kc < 10; ++kc) {          // seq K-chunk
      short8 x0 = *(const short8*)(ap0 + kc*32);
      short8 x1 = *(const short8*)(ap1 + kc*32);
      short8 w0 = *(const short8*)(bp0 + kc*32);
      short8 w1 = *(const short8*)(bp1 + kc*32);
      a00 = __builtin_amdgcn_mfma_f32_16x16x32_bf16(x0, w0, a00, 0, 0, 0);
      a01 = __builtin_amdgcn_mfma_f32_16x16x32_bf16(x0, w1, a01, 0, 0, 0);
      a10 = __builtin_amdgcn_mfma_f32_16x16x32_bf16(x1, w0, a10, 0, 0, 0);
      a11 = __builtin_amdgcn_mfma_f32_16x16x32_bf16(x1, w1, a11, 0, 0, 0);
    }
    #pragma unroll
    for (int kc = 0; kc < 16; ++kc) {          // h K-chunk
      short8 x0 = *(const short8*)(hp0 + kc*32);
      short8 x1 = *(const short8*)(hp1 + kc*32);
      short8 w0 = *(const short8*)(bp0 + (10+kc)*32);
      short8 w1 = *(const short8*)(bp1 + (10+kc)*32);
      a00 = __builtin_amdgcn_mfma_f32_16x16x32_bf16(x0, w0, a00, 0, 0, 0);
      a01 = __builtin_amdgcn_mfma_f32_16x16x32_bf16(x0, w1, a01, 0, 0, 0);
      a10 = __builtin_amdgcn_mfma_f32_16x16x32_bf16(x1, w0, a10, 0, 0, 0);
      a11 = __builtin_amdgcn_mfma_f32_16x16x32_bf16(x1, w1, a11, 0, 0, 0);
    }

    // D layout: row = 4*(lane>>4)+r, col = lane&15 (per 16x16 tile)
    #pragma unroll
    for (int r = 0; r < 4; ++r) {
      gl[(mt0  )*16 + lhi*4 + r][(nt0  )*16 + l16] = a00[r];
      gl[(mt0  )*16 + lhi*4 + r][(nt0+1)*16 + l16] = a01[r];
      gl[(mt0+1)*16 + lhi*4 + r][(nt0  )*16 + l16] = a10[r];
      gl[(mt0+1)*16 + lhi*4 + r][(nt0+1)*16 + l16] = a11[r];
    }
    __syncthreads();

    // fused cell update: 4 cells per thread
    const int gb = b0 + erow;
    #pragma unroll
    for (int u = 0; u < 4; ++u) {
      const int jl = ej + 4*u;
      f32x4 g4 = *(const f32x4*)(&gl[erow][jl*4]);
      f32x4 bia = (u == 0) ? bia0 : (u == 1) ? bia1 : (u == 2) ? bia2 : bia3;
      float iv = sigm  (g4[0] + bia[0]);
      float fv = sigm  (g4[1] + bia[1]);
      float gv = tanhf_(g4[2] + bia[2]);
      float ov = sigm  (g4[3] + bia[3]);
      float& cc = (u == 0) ? c0 : (u == 1) ? c1 : (u == 2) ? c2 : c3;
      cc = fv * cc + iv * gv;
      float h = ov * tanhf_(cc);
      const int jhg = jt*16 + jl;
      y[((size_t)gb*T_ + t)*H_ + jhg] = h;
      ho_[(size_t)gb*H_ + jhg] = f2b(h);
    }

    if (t < T_ - 1) {
      __threadfence();                         // h visible device-wide
      __syncthreads();                         // whole block done writing + gl reads done
      if (tid == 0) {
        __hip_atomic_fetch_add(&bar[bt], 1u, __ATOMIC_RELEASE, __HIP_MEMORY_SCOPE_AGENT);
        while (__hip_atomic_load(&bar[bt], __ATOMIC_ACQUIRE, __HIP_MEMORY_SCOPE_AGENT)
               < 32u*(unsigned)(t+1))
          __builtin_amdgcn_s_sleep(4);
      }
      __syncthreads();                         // acquire (cache inv) ordered before next reads
    }
  }
}

// ============ BN1 partial stats over (B,H) per t ============
__global__ __launch_bounds__(256) void k_bn1part(
    const float* __restrict__ y, float* __restrict__ bn1s, float* __restrict__ bn1q)
{
  const int t = blockIdx.x, ch = blockIdx.y, tid = threadIdx.x;
  float s = 0.f, q = 0.f;
  for (int i = tid; i < 64*H_; i += 256) {
    int b = ch*64 + (i >> 9);
    float v = y[((size_t)b*T_ + t)*H_ + (i & 511)];
    s += v; q += v*v;
  }
  __shared__ float rs[256], rq[256];
  rs[tid] = s; rq[tid] = q;
  __syncthreads();
  for (int o = 128; o; o >>= 1) {
    if (tid < o) { rs[tid] += rs[tid+o]; rq[tid] += rq[tid+o]; }
    __syncthreads();
  }
  if (tid == 0) { bn1s[t*8 + ch] = rs[0]; bn1q[t*8 + ch] = rq[0]; }
}

// ============ head: fold BN1 + (B, T*H) @ Wl^T + bl ============
__global__ __launch_bounds__(256) void k_head(
    const float* __restrict__ y, const float* __restrict__ bn1s, const float* __restrict__ bn1q,
    const float* __restrict__ g1, const float* __restrict__ be1,
    const float* __restrict__ Wl, const float* __restrict__ bl, float* __restrict__ out)
{
  const int b = blockIdx.x, tid = threadIdx.x;
  __shared__ float al1[T_], bt1[T_];
  if (tid < T_) {
    float s = 0.f, q = 0.f;
    #pragma unroll
    for (int ch = 0; ch < 8; ++ch) { s += bn1s[tid*8 + ch]; q += bn1q[tid*8 + ch]; }
    const float cnt = (float)(B_*H_);
    float mu = s / cnt, var = q / cnt - mu*mu;
    float al = g1[tid] * rsqrtf(var + EPS_);
    al1[tid] = al; bt1[tid] = be1[tid] - mu*al;
  }
  __syncthreads();
  float a0 = 0.f, a1 = 0.f, a2 = 0.f;
  const float* yb = y + (size_t)b*(T_*H_);
  for (int i = tid; i < T_*H_; i += 256) {
    int t = i >> 9;
    float yn = yb[i]*al1[t] + bt1[t];
    a0 = fmaf(yn, Wl[i],            a0);
    a1 = fmaf(yn, Wl[T_*H_ + i],    a1);
    a2 = fmaf(yn, Wl[2*T_*H_ + i],  a2);
  }
  __shared__ float red[256];
  red[tid] = a0; __syncthreads();
  for (int o = 128; o; o >>= 1) { if (tid < o) red[tid] += red[tid+o]; __syncthreads(); }
  if (!tid) out[b*3 + 0] = red[0] + bl[0];
  __syncthreads();
  red[tid] = a1; __syncthreads();
  for (int o = 128; o; o >>= 1) { if (tid < o) red[tid] += red[tid+o]; __syncthreads(); }
  if (!tid) out[b*3 + 1] = red[0] + bl[1];
  __syncthreads();
  red[tid] = a2; __syncthreads();
  for (int o = 128; o; o >>= 1) { if (tid < o) red[tid] += red[tid+o]; __syncthreads(); }
  if (!tid) out[b*3 + 2] = red[0] + bl[2];
}

extern "C" void kernel_launch(void* const* d_in, const int* in_sizes, int n_in,
                              void* d_out, int out_size, void* d_ws, size_t ws_size,
                              hipStream_t stream)
{
  (void)in_sizes; (void)n_in; (void)out_size;
  const float* x   = (const float*)d_in[0];
  const int* esrc  = (const int*)d_in[1];
  const int* edst  = (const int*)d_in[2];
  const float* ew  = (const float*)d_in[3];
  const float* Wc  = (const float*)d_in[4];
  const float* bc  = (const float*)d_in[5];
  const float* bng = (const float*)d_in[6];
  const float* bnb = (const float*)d_in[7];
  const float* Wih = (const float*)d_in[8];
  const float* Whh = (const float*)d_in[9];
  const float* bih = (const float*)d_in[10];
  const float* bhh = (const float*)d_in[11];
  const float* g1  = (const float*)d_in[12];
  const float* be1 = (const float*)d_in[13];
  const float* Wl  = (const float*)d_in[14];
  const float* bl  = (const float*)d_in[15];
  float* out = (float*)d_out;

  char* ws = (char*)d_ws;
  size_t off = 0;
  auto alloc = [&](size_t bytes) {
    void* p = ws + off;
    off += (bytes + 255) & ~(size_t)255;
    return p;
  };
  float* cheb = (float*)alloc(sizeof(float)*(size_t)T_*B_*NF_);
  float* bps  = (float*)alloc(sizeof(float)*T_*F_*B_);
  float* bpq  = (float*)alloc(sizeof(float)*T_*F_*B_);
  float* alpha= (float*)alloc(sizeof(float)*T_*F_);
  float* bet  = (float*)alloc(sizeof(float)*T_*F_);
  __hip_bfloat16* seqb = (__hip_bfloat16*)alloc(sizeof(__hip_bfloat16)*(size_t)T_*B_*SEQP);
  __hip_bfloat16* Wcat = (__hip_bfloat16*)alloc(sizeof(__hip_bfloat16)*(size_t)G4*KPAD);
  float* biasr = (float*)alloc(sizeof(float)*G4);
  __hip_bfloat16* h0 = (__hip_bfloat16*)alloc(sizeof(__hip_bfloat16)*B_*H_);
  __hip_bfloat16* h1 = (__hip_bfloat16*)alloc(sizeof(__hip_bfloat16)*B_*H_);
  float* y    = (float*)alloc(sizeof(float)*(size_t)B_*T_*H_);
  float* bn1s = (float*)alloc(sizeof(float)*T_*8);
  float* bn1q = (float*)alloc(sizeof(float)*T_*8);
  unsigned int* bar = (unsigned int*)alloc(sizeof(unsigned int)*8);
  if (ws_size < off) return;   // ~100 MB total (round-5-proven footprint)

  (void)hipMemsetAsync(h0,  0, sizeof(__hip_bfloat16)*B_*H_, stream);
  (void)hipMemsetAsync(bar, 0, sizeof(unsigned int)*8, stream);

  k_cheb<<<dim3(B_, T_/TC), 512, 0, stream>>>(x, esrc, edst, ew, Wc, bc, cheb, bps, bpq);
  k_bnfin<<<T_*F_, 64, 0, stream>>>(bps, bpq, bng, bnb, alpha, bet);
  k_seq<<<(T_*B_*SEQP)/256, 256, 0, stream>>>(cheb, alpha, bet, seqb);
  k_prep<<<G4, 256, 0, stream>>>(Wih, Whh, bih, bhh, Wcat, biasr);

  k_lstm<<<256, 256, 0, stream>>>(seqb, Wcat, biasr, h0, h1, y, bar);

  k_bn1part<<<dim3(T_, 8), 256, 0, stream>>>(y, bn1s, bn1q);
  k_head<<<B_, 256, 0, stream>>>(y, bn1s, bn1q, g1, be1, Wl, bl, out);
}

// Round 7
// 1125.167 us; speedup vs baseline: 2.1379x; 2.1379x over previous
//
#include <hip/hip_runtime.h>
#include <hip/hip_bf16.h>
#include <cstdint>

#define B_ 512
#define T_ 48
#define N_ 62
#define F_ 5
#define E_ 496
#define H_ 512
#define NF_ 310      // N*F
#define SEQP 320     // padded seq row (310 -> 320)
#define KPAD 832     // 320 + 512
#define G4 2048      // 4*H
#define EPS_ 1e-5f
#define TC 12        // t-steps per cheb block (4 chunks)
#define LSTR 72      // LDS row stride in shorts (16B-aligned, conflict-light)

typedef __attribute__((ext_vector_type(8))) short short8;
typedef __attribute__((ext_vector_type(4))) short s16x4;
typedef __attribute__((ext_vector_type(4))) float f32x4;

__device__ __forceinline__ float sigm(float x)  { return 1.f / (1.f + __expf(-x)); }
__device__ __forceinline__ float tanhf_(float x){ return 2.f / (1.f + __expf(-2.f*x)) - 1.f; }

__device__ __forceinline__ short f2b(float v) {   // f32 -> bf16 bits, RN-even
  unsigned int u = __builtin_bit_cast(unsigned int, v);
  unsigned int r = (u + 0x7fffu + ((u >> 16) & 1u)) >> 16;
  return (short)r;
}
__device__ __forceinline__ float b2f(short s) {   // bf16 bits -> f32
  unsigned int u = ((unsigned int)(unsigned short)s) << 16;
  return __builtin_bit_cast(float, u);
}
__device__ __forceinline__ short8 pack_bf16x8(f32x4 a, f32x4 b) {  // 8 f32 -> 8 bf16 (RNE)
  union { short8 s; unsigned int u[4]; } r;
  asm("v_cvt_pk_bf16_f32 %0, %1, %2" : "=v"(r.u[0]) : "v"(a[0]), "v"(a[1]));
  asm("v_cvt_pk_bf16_f32 %0, %1, %2" : "=v"(r.u[1]) : "v"(a[2]), "v"(a[3]));
  asm("v_cvt_pk_bf16_f32 %0, %1, %2" : "=v"(r.u[2]) : "v"(b[0]), "v"(b[1]));
  asm("v_cvt_pk_bf16_f32 %0, %1, %2" : "=v"(r.u[3]) : "v"(b[2]), "v"(b[3]));
  return r.s;
}

// ============ ChebConv K=3 via MFMA + BN partial stats; block = (graph, 12-t chunk) ============
__global__ __launch_bounds__(512) void k_cheb(
    const float* __restrict__ x, const int* __restrict__ esrc, const int* __restrict__ edst,
    const float* __restrict__ ew, const float* __restrict__ Wc, const float* __restrict__ bc,
    float* __restrict__ cheb, float* __restrict__ bps, float* __restrict__ bpq)
{
  __shared__ __align__(16) short SH[4*64*LSTR];   // Lb | Xt | T1t | T2t
  __shared__ float dinv[N_];
  short* Lb  = SH;                 // Lhat bf16 [n][m], 64x64 zero-padded
  short* Xt  = SH + 64*LSTR;       // X^T  bf16 [c=tl*5+f][m=n], 60 rows used
  short* T1t = SH + 2*64*LSTR;     // T1^T
  short* T2t = SH + 3*64*LSTR;     // T2^T
  float* Af  = (float*)T1t;        // f32 A 62x62 = 15376 B overlays T1t+T2t

  const int tid = threadIdx.x;
  const int b = blockIdx.x;
  const int t0 = blockIdx.y * TC;

  for (int i = tid; i < 2*64*LSTR; i += 512) SH[i] = 0;      // zero Lb + Xt
  for (int i = tid; i < N_*N_;     i += 512) Af[i] = 0.f;
  __syncthreads();

  for (int e = tid; e < E_; e += 512)
    atomicAdd(&Af[edst[b*E_ + e]*N_ + esrc[b*E_ + e]], ew[b*E_ + e]);
  for (int i = tid; i < TC*NF_; i += 512) {
    int tl = i / NF_, nf = i - tl*NF_;
    float v = x[((size_t)b*T_ + t0 + tl)*NF_ + nf];
    int n = nf / F_, f = nf - n*F_;
    Xt[(tl*F_ + f)*LSTR + n] = f2b(v);
  }
  __syncthreads();

  if (tid < N_) {
    float s = 0.f;
    for (int m = 0; m < N_; ++m) s += Af[tid*N_ + m];
    dinv[tid] = (s > 0.f) ? rsqrtf(s) : 0.f;
  }
  __syncthreads();
  for (int i = tid; i < N_*N_; i += 512) {
    int n = i / N_, m = i - n*N_;
    Lb[n*LSTR + m] = f2b(-dinv[n] * Af[i] * dinv[m]);
  }
  __syncthreads();

  const int w = tid >> 6, lane = tid & 63, l16 = lane & 15, lhi = lane >> 4;
  const int mt = w >> 1;
  const int nt = (w & 1) * 2;

  // ---- T1 = Lhat @ X ----
  {
    f32x4 acc0 = {0.f,0.f,0.f,0.f}, acc1 = acc0;
    #pragma unroll
    for (int kc = 0; kc < 2; ++kc) {
      short8 a  = *(const short8*)(Lb + (mt*16 + l16)*LSTR + kc*32 + lhi*8);
      short8 b0 = *(const short8*)(Xt + ((nt  )*16 + l16)*LSTR + kc*32 + lhi*8);
      short8 b1 = *(const short8*)(Xt + ((nt+1)*16 + l16)*LSTR + kc*32 + lhi*8);
      acc0 = __builtin_amdgcn_mfma_f32_16x16x32_bf16(a, b0, acc0, 0, 0, 0);
      acc1 = __builtin_amdgcn_mfma_f32_16x16x32_bf16(a, b1, acc1, 0, 0, 0);
    }
    #pragma unroll
    for (int i = 0; i < 2; ++i) {
      f32x4 acc = i ? acc1 : acc0;
      int c = (nt+i)*16 + l16, n = mt*16 + lhi*4;
      s16x4 pk;
      #pragma unroll
      for (int r = 0; r < 4; ++r) pk[r] = f2b(acc[r]);
      *(s16x4*)(T1t + c*LSTR + n) = pk;
    }
  }
  __syncthreads();

  // ---- T2 = 2*Lhat@T1 - X ----
  {
    f32x4 acc0 = {0.f,0.f,0.f,0.f}, acc1 = acc0;
    #pragma unroll
    for (int kc = 0; kc < 2; ++kc) {
      short8 a  = *(const short8*)(Lb + (mt*16 + l16)*LSTR + kc*32 + lhi*8);
      short8 b0 = *(const short8*)(T1t + ((nt  )*16 + l16)*LSTR + kc*32 + lhi*8);
      short8 b1 = *(const short8*)(T1t + ((nt+1)*16 + l16)*LSTR + kc*32 + lhi*8);
      acc0 = __builtin_amdgcn_mfma_f32_16x16x32_bf16(a, b0, acc0, 0, 0, 0);
      acc1 = __builtin_amdgcn_mfma_f32_16x16x32_bf16(a, b1, acc1, 0, 0, 0);
    }
    #pragma unroll
    for (int i = 0; i < 2; ++i) {
      f32x4 acc = i ? acc1 : acc0;
      int c = (nt+i)*16 + l16, n = mt*16 + lhi*4;
      s16x4 xv = *(const s16x4*)(Xt + c*LSTR + n);
      s16x4 pk;
      #pragma unroll
      for (int r = 0; r < 4; ++r) pk[r] = f2b(2.f*acc[r] - b2f(xv[r]));
      *(s16x4*)(T2t + c*LSTR + n) = pk;
    }
  }
  __syncthreads();

  // ---- out[t][n][g] = bc + sum_f X*W0 + T1*W1 + T2*W2 ; + BN partials ----
  const int pair = tid >> 2, q = tid & 3;
  if (pair < TC*F_) {
    const int tl = pair / F_, g = pair - (pair/F_)*F_;
    const int t = t0 + tl;
    float w0[5], w1[5], w2[5];
    #pragma unroll
    for (int ff = 0; ff < 5; ++ff) {
      w0[ff] = Wc[t*75 +      ff*5 + g];
      w1[ff] = Wc[t*75 + 25 + ff*5 + g];
      w2[ff] = Wc[t*75 + 50 + ff*5 + g];
    }
    const float bias = bc[t*F_ + g];
    float ss = 0.f, qq = 0.f;
    float* chout = cheb + ((size_t)t*B_ + b)*NF_;
    #pragma unroll
    for (int grp = 0; grp < 4; ++grp) {
      int n4 = grp*16 + q*4;
      float o[4] = {bias, bias, bias, bias};
      #pragma unroll
      for (int ff = 0; ff < 5; ++ff) {
        int c = tl*F_ + ff;
        s16x4 xv = *(const s16x4*)(Xt  + c*LSTR + n4);
        s16x4 v1 = *(const s16x4*)(T1t + c*LSTR + n4);
        s16x4 v2 = *(const s16x4*)(T2t + c*LSTR + n4);
        #pragma unroll
        for (int i = 0; i < 4; ++i)
          o[i] += b2f(xv[i])*w0[ff] + b2f(v1[i])*w1[ff] + b2f(v2[i])*w2[ff];
      }
      #pragma unroll
      for (int i = 0; i < 4; ++i) {
        int n = n4 + i;
        if (n < N_) { chout[n*F_ + g] = o[i]; ss += o[i]; qq += o[i]*o[i]; }
      }
    }
    ss += __shfl_down(ss, 2, 4); ss += __shfl_down(ss, 1, 4);
    qq += __shfl_down(qq, 2, 4); qq += __shfl_down(qq, 1, 4);
    if (q == 0) { bps[(t*F_ + g)*B_ + b] = ss; bpq[(t*F_ + g)*B_ + b] = qq; }
  }
}

// ============ finalize BN scale/shift per (t,f) ============
__global__ __launch_bounds__(64) void k_bnfin(
    const float* __restrict__ bps, const float* __restrict__ bpq,
    const float* __restrict__ bng, const float* __restrict__ bnb,
    float* __restrict__ alpha, float* __restrict__ bet)
{
  const int tf = blockIdx.x;
  const int lane = threadIdx.x;
  float s = 0.f, q = 0.f;
  for (int i = lane; i < B_; i += 64) { s += bps[tf*B_ + i]; q += bpq[tf*B_ + i]; }
  #pragma unroll
  for (int off = 32; off; off >>= 1) { s += __shfl_down(s, off); q += __shfl_down(q, off); }
  if (lane == 0) {
    const float cnt = (float)(B_*N_);
    float mu = s / cnt;
    float var = q / cnt - mu*mu;
    float al = bng[tf] * rsqrtf(var + EPS_);
    alpha[tf] = al;
    bet[tf] = bnb[tf] - mu*al;
  }
}

// ============ BN apply + pack to bf16 padded sequence [t][b][320] ============
__global__ __launch_bounds__(256) void k_seq(
    const float* __restrict__ cheb, const float* __restrict__ alpha, const float* __restrict__ bet,
    __hip_bfloat16* __restrict__ seqb)
{
  int idx = blockIdx.x*256 + threadIdx.x;     // T*B*320
  int k = idx % SEQP;
  int tb = idx / SEQP;                        // t*B + b
  float v = 0.f;
  if (k < NF_) {
    int t = tb / B_;
    int tf = t*F_ + (k % F_);
    v = cheb[(size_t)tb*NF_ + k] * alpha[tf] + bet[tf];
  }
  seqb[idx] = __float2bfloat16(v);
}

// ============ weight prep: gate-interleaved rows j' = jh*4 + gate; K = [seq|pad|h] ============
__global__ __launch_bounds__(256) void k_prep(
    const float* __restrict__ Wih, const float* __restrict__ Whh,
    const float* __restrict__ bih, const float* __restrict__ bhh,
    __hip_bfloat16* __restrict__ Wcat, float* __restrict__ biasr)
{
  const int jp = blockIdx.x;                  // 0..2047
  const int g = jp & 3, jh = jp >> 2;
  const int jo = g*H_ + jh;
  for (int k = threadIdx.x; k < KPAD; k += 256) {
    float v = 0.f;
    if (k < NF_) v = Wih[(size_t)jo*NF_ + k];
    else if (k >= SEQP) v = Whh[(size_t)jo*H_ + (k - SEQP)];
    Wcat[(size_t)jp*KPAD + k] = __float2bfloat16(v);
  }
  if (threadIdx.x == 0) biasr[jp] = bih[jo] + bhh[jo];
}

// ============ persistent LSTM: weights in VGPRs, h via write-once y, no L2 invalidation ============
// 256 blocks x 256 thr. Block (bt=bid&7, jt=bid>>3): 64(b) x 64(j') tile, all 48 steps.
// Groups of 32 blocks (same bt) exchange h through y (f32, write-once per (b,t)):
// producer release-adds bar[t*8+bt] (drains + wbl2); consumers spin RELAXED (no L2 inv;
// stale reads impossible because each y[.,t,.] address is written exactly once).
__global__ __launch_bounds__(256, 1) void k_lstm(
    const __hip_bfloat16* __restrict__ seqb,   // (T, B, 320) bf16
    const __hip_bfloat16* __restrict__ Wcat,   // (2048, 832) gate-interleaved
    const float* __restrict__ biasr,           // (2048)
    float* __restrict__ y,                     // (B, T, 512) = h history (f32)
    unsigned int* __restrict__ bar)            // (T*8) zeroed
{
  const int tid = threadIdx.x;
  const int bid = blockIdx.x;
  const int bt = bid & 7, jt = bid >> 3;
  const int b0 = bt*64, j0 = jt*64;
  const int w = tid >> 6, lane = tid & 63, l16 = lane & 15, lhi = lane >> 4;
  const int mt0 = (w >> 1) * 2;
  const int nt0 = (w & 1) * 2;

  __shared__ float gl[64][68];

  // ---- preload weight fragments into VGPRs (only weight traffic in this kernel) ----
  short8 wv0[26], wv1[26];
  {
    const short* sw = (const short*)Wcat;
    const short* bp0 = sw + (size_t)(j0 + (nt0  )*16 + l16)*KPAD + lhi*8;
    const short* bp1 = sw + (size_t)(j0 + (nt0+1)*16 + l16)*KPAD + lhi*8;
    #pragma unroll
    for (int kc = 0; kc < 26; ++kc) {
      wv0[kc] = *(const short8*)(bp0 + kc*32);
      wv1[kc] = *(const short8*)(bp1 + kc*32);
    }
  }

  const int erow = tid >> 2, ej = tid & 3;
  float c0 = 0.f, c1 = 0.f, c2 = 0.f, c3 = 0.f;
  f32x4 bia0 = *(const f32x4*)(biasr + j0 + (ej     )*4);
  f32x4 bia1 = *(const f32x4*)(biasr + j0 + (ej +  4)*4);
  f32x4 bia2 = *(const f32x4*)(biasr + j0 + (ej +  8)*4);
  f32x4 bia3 = *(const f32x4*)(biasr + j0 + (ej + 12)*4);

  const float* yr0 = y + (size_t)(b0 + (mt0  )*16 + l16)*T_*H_ + lhi*8;
  const float* yr1 = y + (size_t)(b0 + (mt0+1)*16 + l16)*T_*H_ + lhi*8;

  for (int t = 0; t < T_; ++t) {
    // ---- seq-part (independent of h): runs before the group barrier ----
    const short* sa = (const short*)seqb + (size_t)t*B_*SEQP + lhi*8;
    const short* ap0 = sa + (size_t)(b0 + (mt0  )*16 + l16)*SEQP;
    const short* ap1 = sa + (size_t)(b0 + (mt0+1)*16 + l16)*SEQP;

    f32x4 a00 = {0.f,0.f,0.f,0.f}, a01 = a00, a10 = a00, a11 = a00;
    #pragma unroll
    for (int kc = 0; kc < 10; ++kc) {
      short8 x0 = *(const short8*)(ap0 + kc*32);
      short8 x1 = *(const short8*)(ap1 + kc*32);
      a00 = __builtin_amdgcn_mfma_f32_16x16x32_bf16(x0, wv0[kc], a00, 0, 0, 0);
      a01 = __builtin_amdgcn_mfma_f32_16x16x32_bf16(x0, wv1[kc], a01, 0, 0, 0);
      a10 = __builtin_amdgcn_mfma_f32_16x16x32_bf16(x1, wv0[kc], a10, 0, 0, 0);
      a11 = __builtin_amdgcn_mfma_f32_16x16x32_bf16(x1, wv1[kc], a11, 0, 0, 0);
    }

    // ---- wait for group's step t-1, then h-part from y[.,t-1,.] ----
    if (t > 0) {
      if (tid == 0) {
        while (__hip_atomic_load(&bar[(t-1)*8 + bt], __ATOMIC_RELAXED,
                                 __HIP_MEMORY_SCOPE_AGENT) < 32u)
          __builtin_amdgcn_s_sleep(2);
      }
      __syncthreads();
      __builtin_amdgcn_fence(__ATOMIC_ACQUIRE, "workgroup");

      const float* hp0 = yr0 + (size_t)(t-1)*H_;
      const float* hp1 = yr1 + (size_t)(t-1)*H_;
      #pragma unroll
      for (int kc = 0; kc < 16; ++kc) {
        f32x4 f0a = *(const f32x4*)(hp0 + kc*32);
        f32x4 f0b = *(const f32x4*)(hp0 + kc*32 + 4);
        f32x4 f1a = *(const f32x4*)(hp1 + kc*32);
        f32x4 f1b = *(const f32x4*)(hp1 + kc*32 + 4);
        short8 x0 = pack_bf16x8(f0a, f0b);
        short8 x1 = pack_bf16x8(f1a, f1b);
        a00 = __builtin_amdgcn_mfma_f32_16x16x32_bf16(x0, wv0[10+kc], a00, 0, 0, 0);
        a01 = __builtin_amdgcn_mfma_f32_16x16x32_bf16(x0, wv1[10+kc], a01, 0, 0, 0);
        a10 = __builtin_amdgcn_mfma_f32_16x16x32_bf16(x1, wv0[10+kc], a10, 0, 0, 0);
        a11 = __builtin_amdgcn_mfma_f32_16x16x32_bf16(x1, wv1[10+kc], a11, 0, 0, 0);
      }
    }

    // ---- gather gates in LDS ----
    #pragma unroll
    for (int r = 0; r < 4; ++r) {
      gl[(mt0  )*16 + lhi*4 + r][(nt0  )*16 + l16] = a00[r];
      gl[(mt0  )*16 + lhi*4 + r][(nt0+1)*16 + l16] = a01[r];
      gl[(mt0+1)*16 + lhi*4 + r][(nt0  )*16 + l16] = a10[r];
      gl[(mt0+1)*16 + lhi*4 + r][(nt0+1)*16 + l16] = a11[r];
    }
    __syncthreads();

    // ---- fused cell update: 4 cells/thread ----
    const int gb = b0 + erow;
    #pragma unroll
    for (int u = 0; u < 4; ++u) {
      const int jl = ej + 4*u;
      f32x4 g4 = *(const f32x4*)(&gl[erow][jl*4]);
      f32x4 bia = (u == 0) ? bia0 : (u == 1) ? bia1 : (u == 2) ? bia2 : bia3;
      float iv = sigm  (g4[0] + bia[0]);
      float fv = sigm  (g4[1] + bia[1]);
      float gv = tanhf_(g4[2] + bia[2]);
      float ov = sigm  (g4[3] + bia[3]);
      float& cc = (u == 0) ? c0 : (u == 1) ? c1 : (u == 2) ? c2 : c3;
      cc = fv * cc + iv * gv;
      float h = ov * tanhf_(cc);
      y[((size_t)gb*T_ + t)*H_ + jt*16 + jl] = h;
    }
    __syncthreads();                            // gl reads done; y-writes drained (vmcnt0)

    // ---- signal: release (wbl2) makes this block's y[.,t,.] LLC-visible ----
    if (t < T_ - 1 && tid == 0)
      __hip_atomic_fetch_add(&bar[t*8 + bt], 1u, __ATOMIC_RELEASE,
                             __HIP_MEMORY_SCOPE_AGENT);
  }
}

// ============ BN1 partial stats over (B,H) per t ============
__global__ __launch_bounds__(256) void k_bn1part(
    const float* __restrict__ y, float* __restrict__ bn1s, float* __restrict__ bn1q)
{
  const int t = blockIdx.x, ch = blockIdx.y, tid = threadIdx.x;
  float s = 0.f, q = 0.f;
  for (int i = tid; i < 64*H_; i += 256) {
    int b = ch*64 + (i >> 9);
    float v = y[((size_t)b*T_ + t)*H_ + (i & 511)];
    s += v; q += v*v;
  }
  __shared__ float rs[256], rq[256];
  rs[tid] = s; rq[tid] = q;
  __syncthreads();
  for (int o = 128; o; o >>= 1) {
    if (tid < o) { rs[tid] += rs[tid+o]; rq[tid] += rq[tid+o]; }
    __syncthreads();
  }
  if (tid == 0) { bn1s[t*8 + ch] = rs[0]; bn1q[t*8 + ch] = rq[0]; }
}

// ============ head: fold BN1 + (B, T*H) @ Wl^T + bl ============
__global__ __launch_bounds__(256) void k_head(
    const float* __restrict__ y, const float* __restrict__ bn1s, const float* __restrict__ bn1q,
    const float* __restrict__ g1, const float* __restrict__ be1,
    const float* __restrict__ Wl, const float* __restrict__ bl, float* __restrict__ out)
{
  const int b = blockIdx.x, tid = threadIdx.x;
  __shared__ float al1[T_], bt1[T_];
  if (tid < T_) {
    float s = 0.f, q = 0.f;
    #pragma unroll
    for (int ch = 0; ch < 8; ++ch) { s += bn1s[tid*8 + ch]; q += bn1q[tid*8 + ch]; }
    const float cnt = (float)(B_*H_);
    float mu = s / cnt, var = q / cnt - mu*mu;
    float al = g1[tid] * rsqrtf(var + EPS_);
    al1[tid] = al; bt1[tid] = be1[tid] - mu*al;
  }
  __syncthreads();
  float a0 = 0.f, a1 = 0.f, a2 = 0.f;
  const float* yb = y + (size_t)b*(T_*H_);
  for (int i = tid; i < T_*H_; i += 256) {
    int t = i >> 9;
    float yn = yb[i]*al1[t] + bt1[t];
    a0 = fmaf(yn, Wl[i],            a0);
    a1 = fmaf(yn, Wl[T_*H_ + i],    a1);
    a2 = fmaf(yn, Wl[2*T_*H_ + i],  a2);
  }
  __shared__ float red[256];
  red[tid] = a0; __syncthreads();
  for (int o = 128; o; o >>= 1) { if (tid < o) red[tid] += red[tid+o]; __syncthreads(); }
  if (!tid) out[b*3 + 0] = red[0] + bl[0];
  __syncthreads();
  red[tid] = a1; __syncthreads();
  for (int o = 128; o; o >>= 1) { if (tid < o) red[tid] += red[tid+o]; __syncthreads(); }
  if (!tid) out[b*3 + 1] = red[0] + bl[1];
  __syncthreads();
  red[tid] = a2; __syncthreads();
  for (int o = 128; o; o >>= 1) { if (tid < o) red[tid] += red[tid+o]; __syncthreads(); }
  if (!tid) out[b*3 + 2] = red[0] + bl[2];
}

extern "C" void kernel_launch(void* const* d_in, const int* in_sizes, int n_in,
                              void* d_out, int out_size, void* d_ws, size_t ws_size,
                              hipStream_t stream)
{
  (void)in_sizes; (void)n_in; (void)out_size;
  const float* x   = (const float*)d_in[0];
  const int* esrc  = (const int*)d_in[1];
  const int* edst  = (const int*)d_in[2];
  const float* ew  = (const float*)d_in[3];
  const float* Wc  = (const float*)d_in[4];
  const float* bc  = (const float*)d_in[5];
  const float* bng = (const float*)d_in[6];
  const float* bnb = (const float*)d_in[7];
  const float* Wih = (const float*)d_in[8];
  const float* Whh = (const float*)d_in[9];
  const float* bih = (const float*)d_in[10];
  const float* bhh = (const float*)d_in[11];
  const float* g1  = (const float*)d_in[12];
  const float* be1 = (const float*)d_in[13];
  const float* Wl  = (const float*)d_in[14];
  const float* bl  = (const float*)d_in[15];
  float* out = (float*)d_out;

  char* ws = (char*)d_ws;
  size_t off = 0;
  auto alloc = [&](size_t bytes) {
    void* p = ws + off;
    off += (bytes + 255) & ~(size_t)255;
    return p;
  };
  float* cheb = (float*)alloc(sizeof(float)*(size_t)T_*B_*NF_);
  float* bps  = (float*)alloc(sizeof(float)*T_*F_*B_);
  float* bpq  = (float*)alloc(sizeof(float)*T_*F_*B_);
  float* alpha= (float*)alloc(sizeof(float)*T_*F_);
  float* bet  = (float*)alloc(sizeof(float)*T_*F_);
  __hip_bfloat16* seqb = (__hip_bfloat16*)alloc(sizeof(__hip_bfloat16)*(size_t)T_*B_*SEQP);
  __hip_bfloat16* Wcat = (__hip_bfloat16*)alloc(sizeof(__hip_bfloat16)*(size_t)G4*KPAD);
  float* biasr = (float*)alloc(sizeof(float)*G4);
  float* y    = (float*)alloc(sizeof(float)*(size_t)B_*T_*H_);
  float* bn1s = (float*)alloc(sizeof(float)*T_*8);
  float* bn1q = (float*)alloc(sizeof(float)*T_*8);
  unsigned int* bar = (unsigned int*)alloc(sizeof(unsigned int)*T_*8);
  if (ws_size < off) return;   // ~100 MB (round-5-proven footprint)

  (void)hipMemsetAsync(bar, 0, sizeof(unsigned int)*T_*8, stream);

  k_cheb<<<dim3(B_, T_/TC), 512, 0, stream>>>(x, esrc, edst, ew, Wc, bc, cheb, bps, bpq);
  k_bnfin<<<T_*F_, 64, 0, stream>>>(bps, bpq, bng, bnb, alpha, bet);
  k_seq<<<(T_*B_*SEQP)/256, 256, 0, stream>>>(cheb, alpha, bet, seqb);
  k_prep<<<G4, 256, 0, stream>>>(Wih, Whh, bih, bhh, Wcat, biasr);

  k_lstm<<<256, 256, 0, stream>>>(seqb, Wcat, biasr, y, bar);

  k_bn1part<<<dim3(T_, 8), 256, 0, stream>>>(y, bn1s, bn1q);
  k_head<<<B_, 256, 0, stream>>>(y, bn1s, bn1q, g1, be1, Wl, bl, out);
}

// Round 8
// 695.598 us; speedup vs baseline: 3.4581x; 1.6176x over previous
//
#include <hip/hip_runtime.h>
#include <hip/hip_bf16.h>
#include <cstdint>

#define B_ 512
#define T_ 48
#define N_ 62
#define F_ 5
#define E_ 496
#define H_ 512
#define NF_ 310      // N*F
#define SEQP 320     // padded seq row (310 -> 320)
#define KPAD 832     // 320 + 512
#define G4 2048      // 4*H
#define EPS_ 1e-5f
#define TC 12        // t-steps per cheb block (4 chunks)
#define LSTR 72      // LDS row stride in shorts

typedef __attribute__((ext_vector_type(8))) short short8;
typedef __attribute__((ext_vector_type(4))) short s16x4;
typedef __attribute__((ext_vector_type(4))) float f32x4;
typedef __attribute__((ext_vector_type(2))) unsigned int u32x2_;

__device__ __forceinline__ float sigm(float x)  { return 1.f / (1.f + __expf(-x)); }
__device__ __forceinline__ float tanhf_(float x){ return 2.f / (1.f + __expf(-2.f*x)) - 1.f; }

__device__ __forceinline__ short f2b(float v) {   // f32 -> bf16 bits, RN-even
  unsigned int u = __builtin_bit_cast(unsigned int, v);
  unsigned int r = (u + 0x7fffu + ((u >> 16) & 1u)) >> 16;
  return (short)r;
}
__device__ __forceinline__ float b2f(short s) {   // bf16 bits -> f32
  unsigned int u = ((unsigned int)(unsigned short)s) << 16;
  return __builtin_bit_cast(float, u);
}

// ============ ChebConv K=3 via MFMA + BN partial stats; block = (graph, 12-t chunk) ============
__global__ __launch_bounds__(512) void k_cheb(
    const float* __restrict__ x, const int* __restrict__ esrc, const int* __restrict__ edst,
    const float* __restrict__ ew, const float* __restrict__ Wc, const float* __restrict__ bc,
    float* __restrict__ cheb, float* __restrict__ bps, float* __restrict__ bpq)
{
  __shared__ __align__(16) short SH[4*64*LSTR];   // Lb | Xt | T1t | T2t
  __shared__ float dinv[N_];
  short* Lb  = SH;
  short* Xt  = SH + 64*LSTR;
  short* T1t = SH + 2*64*LSTR;
  short* T2t = SH + 3*64*LSTR;
  float* Af  = (float*)T1t;

  const int tid = threadIdx.x;
  const int b = blockIdx.x;
  const int t0 = blockIdx.y * TC;

  for (int i = tid; i < 2*64*LSTR; i += 512) SH[i] = 0;
  for (int i = tid; i < N_*N_;     i += 512) Af[i] = 0.f;
  __syncthreads();

  for (int e = tid; e < E_; e += 512)
    atomicAdd(&Af[edst[b*E_ + e]*N_ + esrc[b*E_ + e]], ew[b*E_ + e]);
  for (int i = tid; i < TC*NF_; i += 512) {
    int tl = i / NF_, nf = i - tl*NF_;
    float v = x[((size_t)b*T_ + t0 + tl)*NF_ + nf];
    int n = nf / F_, f = nf - n*F_;
    Xt[(tl*F_ + f)*LSTR + n] = f2b(v);
  }
  __syncthreads();

  if (tid < N_) {
    float s = 0.f;
    for (int m = 0; m < N_; ++m) s += Af[tid*N_ + m];
    dinv[tid] = (s > 0.f) ? rsqrtf(s) : 0.f;
  }
  __syncthreads();
  for (int i = tid; i < N_*N_; i += 512) {
    int n = i / N_, m = i - n*N_;
    Lb[n*LSTR + m] = f2b(-dinv[n] * Af[i] * dinv[m]);
  }
  __syncthreads();

  const int w = tid >> 6, lane = tid & 63, l16 = lane & 15, lhi = lane >> 4;
  const int mt = w >> 1;
  const int nt = (w & 1) * 2;

  // ---- T1 = Lhat @ X ----
  {
    f32x4 acc0 = {0.f,0.f,0.f,0.f}, acc1 = acc0;
    #pragma unroll
    for (int kc = 0; kc < 2; ++kc) {
      short8 a  = *(const short8*)(Lb + (mt*16 + l16)*LSTR + kc*32 + lhi*8);
      short8 b0 = *(const short8*)(Xt + ((nt  )*16 + l16)*LSTR + kc*32 + lhi*8);
      short8 b1 = *(const short8*)(Xt + ((nt+1)*16 + l16)*LSTR + kc*32 + lhi*8);
      acc0 = __builtin_amdgcn_mfma_f32_16x16x32_bf16(a, b0, acc0, 0, 0, 0);
      acc1 = __builtin_amdgcn_mfma_f32_16x16x32_bf16(a, b1, acc1, 0, 0, 0);
    }
    #pragma unroll
    for (int i = 0; i < 2; ++i) {
      f32x4 acc = i ? acc1 : acc0;
      int c = (nt+i)*16 + l16, n = mt*16 + lhi*4;
      s16x4 pk;
      #pragma unroll
      for (int r = 0; r < 4; ++r) pk[r] = f2b(acc[r]);
      *(s16x4*)(T1t + c*LSTR + n) = pk;
    }
  }
  __syncthreads();

  // ---- T2 = 2*Lhat@T1 - X ----
  {
    f32x4 acc0 = {0.f,0.f,0.f,0.f}, acc1 = acc0;
    #pragma unroll
    for (int kc = 0; kc < 2; ++kc) {
      short8 a  = *(const short8*)(Lb + (mt*16 + l16)*LSTR + kc*32 + lhi*8);
      short8 b0 = *(const short8*)(T1t + ((nt  )*16 + l16)*LSTR + kc*32 + lhi*8);
      short8 b1 = *(const short8*)(T1t + ((nt+1)*16 + l16)*LSTR + kc*32 + lhi*8);
      acc0 = __builtin_amdgcn_mfma_f32_16x16x32_bf16(a, b0, acc0, 0, 0, 0);
      acc1 = __builtin_amdgcn_mfma_f32_16x16x32_bf16(a, b1, acc1, 0, 0, 0);
    }
    #pragma unroll
    for (int i = 0; i < 2; ++i) {
      f32x4 acc = i ? acc1 : acc0;
      int c = (nt+i)*16 + l16, n = mt*16 + lhi*4;
      s16x4 xv = *(const s16x4*)(Xt + c*LSTR + n);
      s16x4 pk;
      #pragma unroll
      for (int r = 0; r < 4; ++r) pk[r] = f2b(2.f*acc[r] - b2f(xv[r]));
      *(s16x4*)(T2t + c*LSTR + n) = pk;
    }
  }
  __syncthreads();

  // ---- out + BN partials ----
  const int pair = tid >> 2, q = tid & 3;
  if (pair < TC*F_) {
    const int tl = pair / F_, g = pair - (pair/F_)*F_;
    const int t = t0 + tl;
    float w0[5], w1[5], w2[5];
    #pragma unroll
    for (int ff = 0; ff < 5; ++ff) {
      w0[ff] = Wc[t*75 +      ff*5 + g];
      w1[ff] = Wc[t*75 + 25 + ff*5 + g];
      w2[ff] = Wc[t*75 + 50 + ff*5 + g];
    }
    const float bias = bc[t*F_ + g];
    float ss = 0.f, qq = 0.f;
    float* chout = cheb + ((size_t)t*B_ + b)*NF_;
    #pragma unroll
    for (int grp = 0; grp < 4; ++grp) {
      int n4 = grp*16 + q*4;
      float o[4] = {bias, bias, bias, bias};
      #pragma unroll
      for (int ff = 0; ff < 5; ++ff) {
        int c = tl*F_ + ff;
        s16x4 xv = *(const s16x4*)(Xt  + c*LSTR + n4);
        s16x4 v1 = *(const s16x4*)(T1t + c*LSTR + n4);
        s16x4 v2 = *(const s16x4*)(T2t + c*LSTR + n4);
        #pragma unroll
        for (int i = 0; i < 4; ++i)
          o[i] += b2f(xv[i])*w0[ff] + b2f(v1[i])*w1[ff] + b2f(v2[i])*w2[ff];
      }
      #pragma unroll
      for (int i = 0; i < 4; ++i) {
        int n = n4 + i;
        if (n < N_) { chout[n*F_ + g] = o[i]; ss += o[i]; qq += o[i]*o[i]; }
      }
    }
    ss += __shfl_down(ss, 2, 4); ss += __shfl_down(ss, 1, 4);
    qq += __shfl_down(qq, 2, 4); qq += __shfl_down(qq, 1, 4);
    if (q == 0) { bps[(t*F_ + g)*B_ + b] = ss; bpq[(t*F_ + g)*B_ + b] = qq; }
  }
}

// ============ finalize BN scale/shift per (t,f) ============
__global__ __launch_bounds__(64) void k_bnfin(
    const float* __restrict__ bps, const float* __restrict__ bpq,
    const float* __restrict__ bng, const float* __restrict__ bnb,
    float* __restrict__ alpha, float* __restrict__ bet)
{
  const int tf = blockIdx.x;
  const int lane = threadIdx.x;
  float s = 0.f, q = 0.f;
  for (int i = lane; i < B_; i += 64) { s += bps[tf*B_ + i]; q += bpq[tf*B_ + i]; }
  #pragma unroll
  for (int off = 32; off; off >>= 1) { s += __shfl_down(s, off); q += __shfl_down(q, off); }
  if (lane == 0) {
    const float cnt = (float)(B_*N_);
    float mu = s / cnt;
    float var = q / cnt - mu*mu;
    float al = bng[tf] * rsqrtf(var + EPS_);
    alpha[tf] = al;
    bet[tf] = bnb[tf] - mu*al;
  }
}

// ============ BN apply + pack to bf16 padded sequence [t][b][320] ============
__global__ __launch_bounds__(256) void k_seq(
    const float* __restrict__ cheb, const float* __restrict__ alpha, const float* __restrict__ bet,
    __hip_bfloat16* __restrict__ seqb)
{
  int idx = blockIdx.x*256 + threadIdx.x;
  int k = idx % SEQP;
  int tb = idx / SEQP;
  float v = 0.f;
  if (k < NF_) {
    int t = tb / B_;
    int tf = t*F_ + (k % F_);
    v = cheb[(size_t)tb*NF_ + k] * alpha[tf] + bet[tf];
  }
  seqb[idx] = __float2bfloat16(v);
}

// ============ weight prep: gate-interleaved rows j' = jh*4 + gate; K = [seq|pad|h] ============
__global__ __launch_bounds__(256) void k_prep(
    const float* __restrict__ Wih, const float* __restrict__ Whh,
    const float* __restrict__ bih, const float* __restrict__ bhh,
    __hip_bfloat16* __restrict__ Wcat, float* __restrict__ biasr)
{
  const int jp = blockIdx.x;
  const int g = jp & 3, jh = jp >> 2;
  const int jo = g*H_ + jh;
  for (int k = threadIdx.x; k < KPAD; k += 256) {
    float v = 0.f;
    if (k < NF_) v = Wih[(size_t)jo*NF_ + k];
    else if (k >= SEQP) v = Whh[(size_t)jo*H_ + (k - SEQP)];
    Wcat[(size_t)jp*KPAD + k] = __float2bfloat16(v);
  }
  if (threadIdx.x == 0) biasr[jp] = bih[jo] + bhh[jo];
}

// ============ persistent LSTM v3: VGPR-pinned weights, LLC write-through h exchange ============
#define WOP(M)  M(0) M(1) M(2) M(3) M(4) M(5) M(6) M(7) M(8) M(9) M(10) M(11) M(12) M(13) \
                M(14) M(15) M(16) M(17) M(18) M(19) M(20) M(21) M(22) M(23) M(24) M(25)
#define WSEQ(M) M(0) M(1) M(2) M(3) M(4) M(5) M(6) M(7) M(8) M(9)
#define WHP(M)  M(10) M(11) M(12) M(13) M(14) M(15) M(16) M(17) M(18) M(19) M(20) M(21) \
                M(22) M(23) M(24) M(25)

#define DECLW(i) short8 wa##i, wb##i;
#define LOADW(i) wa##i = *(const short8*)(bp0 + (i)*32); \
                 wb##i = *(const short8*)(bp1 + (i)*32); \
                 asm volatile("" : "+v"(wa##i), "+v"(wb##i));
#define MFS(i) { short8 x0 = *(const short8*)(ap0 + (i)*32); \
                 short8 x1 = *(const short8*)(ap1 + (i)*32); \
                 a00 = __builtin_amdgcn_mfma_f32_16x16x32_bf16(x0, wa##i, a00, 0, 0, 0); \
                 a01 = __builtin_amdgcn_mfma_f32_16x16x32_bf16(x0, wb##i, a01, 0, 0, 0); \
                 a10 = __builtin_amdgcn_mfma_f32_16x16x32_bf16(x1, wa##i, a10, 0, 0, 0); \
                 a11 = __builtin_amdgcn_mfma_f32_16x16x32_bf16(x1, wb##i, a11, 0, 0, 0); }
#define MFH(i) { short8 x0 = *(const short8*)(hp0 + ((i)-10)*32); \
                 short8 x1 = *(const short8*)(hp1 + ((i)-10)*32); \
                 a00 = __builtin_amdgcn_mfma_f32_16x16x32_bf16(x0, wa##i, a00, 0, 0, 0); \
                 a01 = __builtin_amdgcn_mfma_f32_16x16x32_bf16(x0, wb##i, a01, 0, 0, 0); \
                 a10 = __builtin_amdgcn_mfma_f32_16x16x32_bf16(x1, wa##i, a10, 0, 0, 0); \
                 a11 = __builtin_amdgcn_mfma_f32_16x16x32_bf16(x1, wb##i, a11, 0, 0, 0); }

__global__ __launch_bounds__(256, 1) void k_lstm(
    const __hip_bfloat16* __restrict__ seqb,   // (T, B, 320) bf16
    const __hip_bfloat16* __restrict__ Wcat,   // (2048, 832) gate-interleaved
    const float* __restrict__ biasr,           // (2048)
    __hip_bfloat16* __restrict__ hb,           // (T, B, 512) bf16  = h history (write-once)
    unsigned int* __restrict__ bar)            // (T*8) zeroed
{
  const int tid = threadIdx.x;
  const int bid = blockIdx.x;
  const int bt = bid & 7, jt = bid >> 3;
  const int b0 = bt*64, j0 = jt*64;
  const int w = tid >> 6, lane = tid & 63, l16 = lane & 15, lhi = lane >> 4;
  const int mt0 = (w >> 1) * 2;
  const int nt0 = (w & 1) * 2;

  __shared__ float gl[64][68];

  // ---- pin all 52 weight fragments in VGPRs (208 regs) ----
  const short* sw = (const short*)Wcat;
  const short* bp0 = sw + (size_t)(j0 + (nt0  )*16 + l16)*KPAD + lhi*8;
  const short* bp1 = sw + (size_t)(j0 + (nt0+1)*16 + l16)*KPAD + lhi*8;
  WOP(DECLW)
  WOP(LOADW)

  const int erow = tid >> 2, ej = tid & 3;
  float c0 = 0.f, c1 = 0.f, c2 = 0.f, c3 = 0.f;
  f32x4 bia0 = *(const f32x4*)(biasr + j0 + ej*16 + 0);
  f32x4 bia1 = *(const f32x4*)(biasr + j0 + ej*16 + 4);
  f32x4 bia2 = *(const f32x4*)(biasr + j0 + ej*16 + 8);
  f32x4 bia3 = *(const f32x4*)(biasr + j0 + ej*16 + 12);

  short* hbs = (short*)hb;
  const int r0 = b0 + mt0*16 + l16;            // this wave's two A rows
  const int r1 = b0 + (mt0+1)*16 + l16;

  #pragma unroll 1
  for (int t = 0; t < T_; ++t) {
    // ---- seq-part (no h dependence) before the group wait ----
    const short* sa = (const short*)seqb + (size_t)t*B_*SEQP + lhi*8;
    const short* ap0 = sa + (size_t)r0*SEQP;
    const short* ap1 = sa + (size_t)r1*SEQP;
    f32x4 a00 = {0.f,0.f,0.f,0.f}, a01 = a00, a10 = a00, a11 = a00;
    WSEQ(MFS)

    // ---- wait for group's h(t-1), then h-part straight from bf16 hbuf ----
    if (t > 0) {
      if (tid == 0) {
        while (__hip_atomic_load(&bar[(t-1)*8 + bt], __ATOMIC_RELAXED,
                                 __HIP_MEMORY_SCOPE_AGENT) < 32u)
          __builtin_amdgcn_s_sleep(1);
      }
      __syncthreads();                         // fences: loads below can't hoist above
      const short* hbase = hbs + (size_t)(t-1)*B_*H_ + lhi*8;
      const short* hp0 = hbase + (size_t)r0*H_;
      const short* hp1 = hbase + (size_t)r1*H_;
      WHP(MFH)
    }

    // ---- gather gates in LDS ----
    #pragma unroll
    for (int r = 0; r < 4; ++r) {
      gl[(mt0  )*16 + lhi*4 + r][(nt0  )*16 + l16] = a00[r];
      gl[(mt0  )*16 + lhi*4 + r][(nt0+1)*16 + l16] = a01[r];
      gl[(mt0+1)*16 + lhi*4 + r][(nt0  )*16 + l16] = a10[r];
      gl[(mt0+1)*16 + lhi*4 + r][(nt0+1)*16 + l16] = a11[r];
    }
    __syncthreads();

    // ---- fused cell update: 4 consecutive hidden units per thread ----
    float h0v, h1v, h2v, h3v;
    {
      f32x4 g4; float iv, fv, gv, ov;
      g4 = *(const f32x4*)(&gl[erow][ej*16 + 0]);
      iv = sigm(g4[0]+bia0[0]); fv = sigm(g4[1]+bia0[1]);
      gv = tanhf_(g4[2]+bia0[2]); ov = sigm(g4[3]+bia0[3]);
      c0 = fv*c0 + iv*gv; h0v = ov*tanhf_(c0);
      g4 = *(const f32x4*)(&gl[erow][ej*16 + 4]);
      iv = sigm(g4[0]+bia1[0]); fv = sigm(g4[1]+bia1[1]);
      gv = tanhf_(g4[2]+bia1[2]); ov = sigm(g4[3]+bia1[3]);
      c1 = fv*c1 + iv*gv; h1v = ov*tanhf_(c1);
      g4 = *(const f32x4*)(&gl[erow][ej*16 + 8]);
      iv = sigm(g4[0]+bia2[0]); fv = sigm(g4[1]+bia2[1]);
      gv = tanhf_(g4[2]+bia2[2]); ov = sigm(g4[3]+bia2[3]);
      c2 = fv*c2 + iv*gv; h2v = ov*tanhf_(c2);
      g4 = *(const f32x4*)(&gl[erow][ej*16 + 12]);
      iv = sigm(g4[0]+bia3[0]); fv = sigm(g4[1]+bia3[1]);
      gv = tanhf_(g4[2]+bia3[2]); ov = sigm(g4[3]+bia3[3]);
      c3 = fv*c3 + iv*gv; h3v = ov*tanhf_(c3);
    }

    // ---- pack 4 h -> bf16x4, store through to LLC (sc0 sc1) ----
    {
      unsigned int d0, d1;
      asm("v_cvt_pk_bf16_f32 %0, %1, %2" : "=v"(d0) : "v"(h0v), "v"(h1v));
      asm("v_cvt_pk_bf16_f32 %0, %1, %2" : "=v"(d1) : "v"(h2v), "v"(h3v));
      u32x2_ dd; dd[0] = d0; dd[1] = d1;
      short* dst = hbs + ((size_t)t*B_ + b0 + erow)*H_ + jt*16 + ej*4;
      asm volatile("global_store_dwordx2 %0, %1, off sc0 sc1"
                   :: "v"(dst), "v"(dd) : "memory");
    }
    __syncthreads();                           // drains vmcnt for ALL threads' stores

    if (t < T_ - 1 && tid == 0)
      __hip_atomic_fetch_add(&bar[t*8 + bt], 1u, __ATOMIC_RELAXED,
                             __HIP_MEMORY_SCOPE_AGENT);
  }
}

// ============ BN1 partial stats over (B,H) per t — reads bf16 hbuf[t][b][h] ============
__global__ __launch_bounds__(256) void k_bn1part(
    const __hip_bfloat16* __restrict__ hb, float* __restrict__ bn1s, float* __restrict__ bn1q)
{
  const int t = blockIdx.x, ch = blockIdx.y, tid = threadIdx.x;
  const short* base = (const short*)hb + ((size_t)t*B_ + ch*64)*H_;
  float s = 0.f, q = 0.f;
  for (int i = tid; i < 64*H_/8; i += 256) {
    short8 v8 = *(const short8*)(base + (i>>6)*H_ + (i&63)*8);
    #pragma unroll
    for (int j = 0; j < 8; ++j) { float v = b2f(v8[j]); s += v; q += v*v; }
  }
  __shared__ float rs[256], rq[256];
  rs[tid] = s; rq[tid] = q;
  __syncthreads();
  for (int o = 128; o; o >>= 1) {
    if (tid < o) { rs[tid] += rs[tid+o]; rq[tid] += rq[tid+o]; }
    __syncthreads();
  }
  if (tid == 0) { bn1s[t*8 + ch] = rs[0]; bn1q[t*8 + ch] = rq[0]; }
}

// ============ head: fold BN1 + (B, T*H) @ Wl^T + bl — reads bf16 hbuf ============
__global__ __launch_bounds__(256) void k_head(
    const __hip_bfloat16* __restrict__ hb, const float* __restrict__ bn1s,
    const float* __restrict__ bn1q, const float* __restrict__ g1,
    const float* __restrict__ be1, const float* __restrict__ Wl,
    const float* __restrict__ bl, float* __restrict__ out)
{
  const int b = blockIdx.x, tid = threadIdx.x;
  __shared__ float al1[T_], bt1[T_];
  if (tid < T_) {
    float s = 0.f, q = 0.f;
    #pragma unroll
    for (int ch = 0; ch < 8; ++ch) { s += bn1s[tid*8 + ch]; q += bn1q[tid*8 + ch]; }
    const float cnt = (float)(B_*H_);
    float mu = s / cnt, var = q / cnt - mu*mu;
    float al = g1[tid] * rsqrtf(var + EPS_);
    al1[tid] = al; bt1[tid] = be1[tid] - mu*al;
  }
  __syncthreads();
  float a0 = 0.f, a1 = 0.f, a2 = 0.f;
  const short* hbs = (const short*)hb;
  for (int i8 = tid; i8 < (T_*H_)/8; i8 += 256) {
    const int t = i8 >> 6, h8 = (i8 & 63)*8;
    short8 v8 = *(const short8*)(hbs + ((size_t)t*B_ + b)*H_ + h8);
    const int wi = t*H_ + h8;
    #pragma unroll
    for (int j = 0; j < 8; ++j) {
      float yn = b2f(v8[j])*al1[t] + bt1[t];
      a0 = fmaf(yn, Wl[wi + j],            a0);
      a1 = fmaf(yn, Wl[T_*H_ + wi + j],    a1);
      a2 = fmaf(yn, Wl[2*T_*H_ + wi + j],  a2);
    }
  }
  __shared__ float red[256];
  red[tid] = a0; __syncthreads();
  for (int o = 128; o; o >>= 1) { if (tid < o) red[tid] += red[tid+o]; __syncthreads(); }
  if (!tid) out[b*3 + 0] = red[0] + bl[0];
  __syncthreads();
  red[tid] = a1; __syncthreads();
  for (int o = 128; o; o >>= 1) { if (tid < o) red[tid] += red[tid+o]; __syncthreads(); }
  if (!tid) out[b*3 + 1] = red[0] + bl[1];
  __syncthreads();
  red[tid] = a2; __syncthreads();
  for (int o = 128; o; o >>= 1) { if (tid < o) red[tid] += red[tid+o]; __syncthreads(); }
  if (!tid) out[b*3 + 2] = red[0] + bl[2];
}

extern "C" void kernel_launch(void* const* d_in, const int* in_sizes, int n_in,
                              void* d_out, int out_size, void* d_ws, size_t ws_size,
                              hipStream_t stream)
{
  (void)in_sizes; (void)n_in; (void)out_size;
  const float* x   = (const float*)d_in[0];
  const int* esrc  = (const int*)d_in[1];
  const int* edst  = (const int*)d_in[2];
  const float* ew  = (const float*)d_in[3];
  const float* Wc  = (const float*)d_in[4];
  const float* bc  = (const float*)d_in[5];
  const float* bng = (const float*)d_in[6];
  const float* bnb = (const float*)d_in[7];
  const float* Wih = (const float*)d_in[8];
  const float* Whh = (const float*)d_in[9];
  const float* bih = (const float*)d_in[10];
  const float* bhh = (const float*)d_in[11];
  const float* g1  = (const float*)d_in[12];
  const float* be1 = (const float*)d_in[13];
  const float* Wl  = (const float*)d_in[14];
  const float* bl  = (const float*)d_in[15];
  float* out = (float*)d_out;

  char* ws = (char*)d_ws;
  size_t off = 0;
  auto alloc = [&](size_t bytes) {
    void* p = ws + off;
    off += (bytes + 255) & ~(size_t)255;
    return p;
  };
  float* cheb = (float*)alloc(sizeof(float)*(size_t)T_*B_*NF_);
  float* bps  = (float*)alloc(sizeof(float)*T_*F_*B_);
  float* bpq  = (float*)alloc(sizeof(float)*T_*F_*B_);
  float* alpha= (float*)alloc(sizeof(float)*T_*F_);
  float* bet  = (float*)alloc(sizeof(float)*T_*F_);
  __hip_bfloat16* seqb = (__hip_bfloat16*)alloc(sizeof(__hip_bfloat16)*(size_t)T_*B_*SEQP);
  __hip_bfloat16* Wcat = (__hip_bfloat16*)alloc(sizeof(__hip_bfloat16)*(size_t)G4*KPAD);
  float* biasr = (float*)alloc(sizeof(float)*G4);
  __hip_bfloat16* hbuf = (__hip_bfloat16*)alloc(sizeof(__hip_bfloat16)*(size_t)T_*B_*H_);
  float* bn1s = (float*)alloc(sizeof(float)*T_*8);
  float* bn1q = (float*)alloc(sizeof(float)*T_*8);
  unsigned int* bar = (unsigned int*)alloc(sizeof(unsigned int)*T_*8);
  if (ws_size < off) return;   // ~75 MB — well within proven budget

  (void)hipMemsetAsync(bar, 0, sizeof(unsigned int)*T_*8, stream);

  k_cheb<<<dim3(B_, T_/TC), 512, 0, stream>>>(x, esrc, edst, ew, Wc, bc, cheb, bps, bpq);
  k_bnfin<<<T_*F_, 64, 0, stream>>>(bps, bpq, bng, bnb, alpha, bet);
  k_seq<<<(T_*B_*SEQP)/256, 256, 0, stream>>>(cheb, alpha, bet, seqb);
  k_prep<<<G4, 256, 0, stream>>>(Wih, Whh, bih, bhh, Wcat, biasr);

  k_lstm<<<256, 256, 0, stream>>>(seqb, Wcat, biasr, hbuf, bar);

  k_bn1part<<<dim3(T_, 8), 256, 0, stream>>>(hbuf, bn1s, bn1q);
  k_head<<<B_, 256, 0, stream>>>(hbuf, bn1s, bn1q, g1, be1, Wl, bl, out);
}

// Round 9
// 342.696 us; speedup vs baseline: 7.0193x; 2.0298x over previous
//
#include <hip/hip_runtime.h>
#include <hip/hip_bf16.h>
#include <cstdint>

#define B_ 512
#define T_ 48
#define N_ 62
#define F_ 5
#define E_ 496
#define H_ 512
#define NF_ 310      // N*F
#define SEQP 320     // padded seq row (310 -> 320)
#define KPAD 832     // 320 + 512
#define G4 2048      // 4*H
#define EPS_ 1e-5f
#define TC 12        // t-steps per cheb block (4 chunks)
#define LSTR 72      // LDS row stride in shorts

typedef __attribute__((ext_vector_type(8))) short short8;
typedef __attribute__((ext_vector_type(4))) short s16x4;
typedef __attribute__((ext_vector_type(4))) float f32x4;

__device__ __forceinline__ float sigm(float x)  { return 1.f / (1.f + __expf(-x)); }
__device__ __forceinline__ float tanhf_(float x){ return 2.f / (1.f + __expf(-2.f*x)) - 1.f; }

__device__ __forceinline__ short f2b(float v) {   // f32 -> bf16 bits, RN-even
  unsigned int u = __builtin_bit_cast(unsigned int, v);
  unsigned int r = (u + 0x7fffu + ((u >> 16) & 1u)) >> 16;
  return (short)r;
}
__device__ __forceinline__ float b2f(short s) {
  unsigned int u = ((unsigned int)(unsigned short)s) << 16;
  return __builtin_bit_cast(float, u);
}

__device__ __forceinline__ void dma16(const void* g, void* l) {
  __builtin_amdgcn_global_load_lds(
      (const __attribute__((address_space(1))) unsigned int*)g,
      (__attribute__((address_space(3))) unsigned int*)l, 16, 0, 0);
}

// ============ ChebConv K=3 via MFMA + BN partial stats; block = (graph, 12-t chunk) ============
__global__ __launch_bounds__(512) void k_cheb(
    const float* __restrict__ x, const int* __restrict__ esrc, const int* __restrict__ edst,
    const float* __restrict__ ew, const float* __restrict__ Wc, const float* __restrict__ bc,
    float* __restrict__ cheb, float* __restrict__ bps, float* __restrict__ bpq)
{
  __shared__ __align__(16) short SH[4*64*LSTR];
  __shared__ float dinv[N_];
  short* Lb  = SH;
  short* Xt  = SH + 64*LSTR;
  short* T1t = SH + 2*64*LSTR;
  short* T2t = SH + 3*64*LSTR;
  float* Af  = (float*)T1t;

  const int tid = threadIdx.x;
  const int b = blockIdx.x;
  const int t0 = blockIdx.y * TC;

  for (int i = tid; i < 2*64*LSTR; i += 512) SH[i] = 0;
  for (int i = tid; i < N_*N_;     i += 512) Af[i] = 0.f;
  __syncthreads();

  for (int e = tid; e < E_; e += 512)
    atomicAdd(&Af[edst[b*E_ + e]*N_ + esrc[b*E_ + e]], ew[b*E_ + e]);
  for (int i = tid; i < TC*NF_; i += 512) {
    int tl = i / NF_, nf = i - tl*NF_;
    float v = x[((size_t)b*T_ + t0 + tl)*NF_ + nf];
    int n = nf / F_, f = nf - n*F_;
    Xt[(tl*F_ + f)*LSTR + n] = f2b(v);
  }
  __syncthreads();

  if (tid < N_) {
    float s = 0.f;
    for (int m = 0; m < N_; ++m) s += Af[tid*N_ + m];
    dinv[tid] = (s > 0.f) ? rsqrtf(s) : 0.f;
  }
  __syncthreads();
  for (int i = tid; i < N_*N_; i += 512) {
    int n = i / N_, m = i - n*N_;
    Lb[n*LSTR + m] = f2b(-dinv[n] * Af[i] * dinv[m]);
  }
  __syncthreads();

  const int w = tid >> 6, lane = tid & 63, l16 = lane & 15, lhi = lane >> 4;
  const int mt = w >> 1;
  const int nt = (w & 1) * 2;

  {
    f32x4 acc0 = {0.f,0.f,0.f,0.f}, acc1 = acc0;
    #pragma unroll
    for (int kc = 0; kc < 2; ++kc) {
      short8 a  = *(const short8*)(Lb + (mt*16 + l16)*LSTR + kc*32 + lhi*8);
      short8 b0 = *(const short8*)(Xt + ((nt  )*16 + l16)*LSTR + kc*32 + lhi*8);
      short8 b1 = *(const short8*)(Xt + ((nt+1)*16 + l16)*LSTR + kc*32 + lhi*8);
      acc0 = __builtin_amdgcn_mfma_f32_16x16x32_bf16(a, b0, acc0, 0, 0, 0);
      acc1 = __builtin_amdgcn_mfma_f32_16x16x32_bf16(a, b1, acc1, 0, 0, 0);
    }
    #pragma unroll
    for (int i = 0; i < 2; ++i) {
      f32x4 acc = i ? acc1 : acc0;
      int c = (nt+i)*16 + l16, n = mt*16 + lhi*4;
      s16x4 pk;
      #pragma unroll
      for (int r = 0; r < 4; ++r) pk[r] = f2b(acc[r]);
      *(s16x4*)(T1t + c*LSTR + n) = pk;
    }
  }
  __syncthreads();

  {
    f32x4 acc0 = {0.f,0.f,0.f,0.f}, acc1 = acc0;
    #pragma unroll
    for (int kc = 0; kc < 2; ++kc) {
      short8 a  = *(const short8*)(Lb + (mt*16 + l16)*LSTR + kc*32 + lhi*8);
      short8 b0 = *(const short8*)(T1t + ((nt  )*16 + l16)*LSTR + kc*32 + lhi*8);
      short8 b1 = *(const short8*)(T1t + ((nt+1)*16 + l16)*LSTR + kc*32 + lhi*8);
      acc0 = __builtin_amdgcn_mfma_f32_16x16x32_bf16(a, b0, acc0, 0, 0, 0);
      acc1 = __builtin_amdgcn_mfma_f32_16x16x32_bf16(a, b1, acc1, 0, 0, 0);
    }
    #pragma unroll
    for (int i = 0; i < 2; ++i) {
      f32x4 acc = i ? acc1 : acc0;
      int c = (nt+i)*16 + l16, n = mt*16 + lhi*4;
      s16x4 xv = *(const s16x4*)(Xt + c*LSTR + n);
      s16x4 pk;
      #pragma unroll
      for (int r = 0; r < 4; ++r) pk[r] = f2b(2.f*acc[r] - b2f(xv[r]));
      *(s16x4*)(T2t + c*LSTR + n) = pk;
    }
  }
  __syncthreads();

  const int pair = tid >> 2, q = tid & 3;
  if (pair < TC*F_) {
    const int tl = pair / F_, g = pair - (pair/F_)*F_;
    const int t = t0 + tl;
    float w0[5], w1[5], w2[5];
    #pragma unroll
    for (int ff = 0; ff < 5; ++ff) {
      w0[ff] = Wc[t*75 +      ff*5 + g];
      w1[ff] = Wc[t*75 + 25 + ff*5 + g];
      w2[ff] = Wc[t*75 + 50 + ff*5 + g];
    }
    const float bias = bc[t*F_ + g];
    float ss = 0.f, qq = 0.f;
    float* chout = cheb + ((size_t)t*B_ + b)*NF_;
    #pragma unroll
    for (int grp = 0; grp < 4; ++grp) {
      int n4 = grp*16 + q*4;
      float o[4] = {bias, bias, bias, bias};
      #pragma unroll
      for (int ff = 0; ff < 5; ++ff) {
        int c = tl*F_ + ff;
        s16x4 xv = *(const s16x4*)(Xt  + c*LSTR + n4);
        s16x4 v1 = *(const s16x4*)(T1t + c*LSTR + n4);
        s16x4 v2 = *(const s16x4*)(T2t + c*LSTR + n4);
        #pragma unroll
        for (int i = 0; i < 4; ++i)
          o[i] += b2f(xv[i])*w0[ff] + b2f(v1[i])*w1[ff] + b2f(v2[i])*w2[ff];
      }
      #pragma unroll
      for (int i = 0; i < 4; ++i) {
        int n = n4 + i;
        if (n < N_) { chout[n*F_ + g] = o[i]; ss += o[i]; qq += o[i]*o[i]; }
      }
    }
    ss += __shfl_down(ss, 2, 4); ss += __shfl_down(ss, 1, 4);
    qq += __shfl_down(qq, 2, 4); qq += __shfl_down(qq, 1, 4);
    if (q == 0) { bps[(t*F_ + g)*B_ + b] = ss; bpq[(t*F_ + g)*B_ + b] = qq; }
  }
}

// ============ finalize BN scale/shift per (t,f) ============
__global__ __launch_bounds__(64) void k_bnfin(
    const float* __restrict__ bps, const float* __restrict__ bpq,
    const float* __restrict__ bng, const float* __restrict__ bnb,
    float* __restrict__ alpha, float* __restrict__ bet)
{
  const int tf = blockIdx.x;
  const int lane = threadIdx.x;
  float s = 0.f, q = 0.f;
  for (int i = lane; i < B_; i += 64) { s += bps[tf*B_ + i]; q += bpq[tf*B_ + i]; }
  #pragma unroll
  for (int off = 32; off; off >>= 1) { s += __shfl_down(s, off); q += __shfl_down(q, off); }
  if (lane == 0) {
    const float cnt = (float)(B_*N_);
    float mu = s / cnt;
    float var = q / cnt - mu*mu;
    float al = bng[tf] * rsqrtf(var + EPS_);
    alpha[tf] = al;
    bet[tf] = bnb[tf] - mu*al;
  }
}

// ============ BN apply + pack to bf16 PRE-SWIZZLED sequence [t][b][320] ============
// global slot p holds logical slot (p ^ (b&7)); linear DMA -> LDS then
// ds_read with XOR recovers logical data bank-conflict-free.
__global__ __launch_bounds__(256) void k_seq(
    const float* __restrict__ cheb, const float* __restrict__ alpha, const float* __restrict__ bet,
    __hip_bfloat16* __restrict__ seqb)
{
  int idx = blockIdx.x*256 + threadIdx.x;     // T*B*320
  int kp = idx % SEQP;                        // physical position
  int tb = idx / SEQP;
  int b = tb & (B_-1), t = tb >> 9;
  int sl = (kp >> 3) ^ (b & 7);               // logical slot
  int kl = sl*8 + (kp & 7);                   // logical element
  float v = 0.f;
  if (kl < NF_) v = cheb[(size_t)tb*NF_ + kl] * alpha[t*F_ + (kl % F_)] + bet[t*F_ + (kl % F_)];
  seqb[idx] = __float2bfloat16(v);
}

// ============ weight prep: gate-interleaved rows j' = jh*4 + gate; K = [seq-logical|pad|h] ============
// NOTE: Wcat keeps LOGICAL k-order; only the A-side (seqb/hbuf) is swizzled.
__global__ __launch_bounds__(256) void k_prep(
    const float* __restrict__ Wih, const float* __restrict__ Whh,
    const float* __restrict__ bih, const float* __restrict__ bhh,
    __hip_bfloat16* __restrict__ Wcat, float* __restrict__ biasr)
{
  const int jp = blockIdx.x;
  const int g = jp & 3, jh = jp >> 2;
  const int jo = g*H_ + jh;
  for (int k = threadIdx.x; k < KPAD; k += 256) {
    float v = 0.f;
    if (k < NF_) v = Wih[(size_t)jo*NF_ + k];
    else if (k >= SEQP) v = Whh[(size_t)jo*H_ + (k - SEQP)];
    Wcat[(size_t)jp*KPAD + k] = __float2bfloat16(v);
  }
  if (threadIdx.x == 0) biasr[jp] = bih[jo] + bhh[jo];
}

// ============ persistent LSTM v4: LDS-DMA panels, VGPR weights, write-once swizzled hbuf ============
// 512 blocks x 256 thr (2 blocks/CU). Block (rg=bid&15, jt=bid>>4): 32 b-rows x 64 j'-cols.
// 16 row-groups of 32 blocks sync via relaxed agent atomics; h exchanged through
// write-once hbuf[t][b][512] (bf16, slot-swizzled by b&7), stored sc0 sc1 (to LLC).
#define WOP(M)  M(0) M(1) M(2) M(3) M(4) M(5) M(6) M(7) M(8) M(9) M(10) M(11) M(12) M(13) \
                M(14) M(15) M(16) M(17) M(18) M(19) M(20) M(21) M(22) M(23) M(24) M(25)
#define WSEQ(M) M(0) M(1) M(2) M(3) M(4) M(5) M(6) M(7) M(8) M(9)
#define WHP(M)  M(10) M(11) M(12) M(13) M(14) M(15) M(16) M(17) M(18) M(19) M(20) M(21) \
                M(22) M(23) M(24) M(25)

#define DECLW(i) short8 wv##i;
#define LOADW(i) wv##i = *(const short8*)(wp + (i)*32); \
                 asm volatile("" : "+v"(wv##i));
#define MFS(i) { const int ph = (((i)*4 + lhi) ^ key)*8; \
                 short8 x0 = *(const short8*)(lseq + rs0*SEQP + ph); \
                 short8 x1 = *(const short8*)(lseq + rs1*SEQP + ph); \
                 a0 = __builtin_amdgcn_mfma_f32_16x16x32_bf16(x0, wv##i, a0, 0, 0, 0); \
                 a1 = __builtin_amdgcn_mfma_f32_16x16x32_bf16(x1, wv##i, a1, 0, 0, 0); }
#define MFH(i) { const int ph = ((((i)-10)*4 + lhi) ^ key)*8; \
                 short8 x0 = *(const short8*)(lh + rs0*H_ + ph); \
                 short8 x1 = *(const short8*)(lh + rs1*H_ + ph); \
                 a0 = __builtin_amdgcn_mfma_f32_16x16x32_bf16(x0, wv##i, a0, 0, 0, 0); \
                 a1 = __builtin_amdgcn_mfma_f32_16x16x32_bf16(x1, wv##i, a1, 0, 0, 0); }

__global__ __launch_bounds__(256, 2) void k_lstm(
    const __hip_bfloat16* __restrict__ seqb,   // (T, B, 320) bf16, slot-swizzled
    const __hip_bfloat16* __restrict__ Wcat,   // (2048, 832) gate-interleaved
    const float* __restrict__ biasr,           // (2048)
    __hip_bfloat16* __restrict__ hb,           // (T, B, 512) bf16, slot-swizzled, write-once
    unsigned int* __restrict__ bar)            // (T*16) zeroed
{
  __shared__ __align__(16) short lh[32*H_];    // 32 KB: h panel (overlaid by gl after WHP)
  __shared__ __align__(16) short lseq[32*SEQP];// 20 KB: seq panel
  float (*gl)[68] = (float (*)[68])lh;         // 32x68 f32 = 8.7 KB overlay

  const int tid = threadIdx.x;
  const int bid = blockIdx.x;
  const int rg = bid & 15, jt = bid >> 4;
  const int b0 = rg*32, j0 = jt*64;
  const int w = tid >> 6, lane = tid & 63, l16 = lane & 15, lhi = lane >> 4;
  const int key = l16 & 7;
  const int rs0 = l16, rs1 = l16 + 16;         // local A rows for the two M-tiles

  // ---- pin this wave's 26 weight fragments (col-tile nt = w) ----
  const short* wp = (const short*)Wcat + (size_t)(j0 + w*16 + l16)*KPAD + lhi*8;
  WOP(DECLW)
  WOP(LOADW)

  // ---- cell-update thread mapping: row = tid>>3 (32), u2 = tid&7 (2 units each) ----
  const int crow = tid >> 3, u2 = tid & 7;
  const int hrow = b0 + crow;
  float cc0 = 0.f, cc1 = 0.f;
  f32x4 biaA = *(const f32x4*)(biasr + j0 + u2*8 + 0);
  f32x4 biaB = *(const f32x4*)(biasr + j0 + u2*8 + 4);
  // h-store address (swizzled): slot = jt*2 + (u2>>2); phys = slot ^ (hrow&7)
  const int hslot = (jt*2 + (u2 >> 2)) ^ (hrow & 7);
  const int hoff = hslot*8 + (u2 & 3)*2;

  const char* gseq = (const char*)seqb;
  const char* ghb  = (const char*)hb;
  char* lsc = (char*)lseq;
  char* lhc = (char*)lh;

  // prologue: stage seq(0)
  {
    const char* gs = gseq + ((size_t)b0)*640;
    #pragma unroll
    for (int i = 0; i < 5; ++i) {
      int c = w*5 + i;
      dma16(gs + c*1024 + lane*16, lsc + c*1024);
    }
  }

  #pragma unroll 1
  for (int t = 0; t < T_; ++t) {
    if (t > 0 && tid == 0) {
      while (__hip_atomic_load(&bar[(t-1)*16 + rg], __ATOMIC_RELAXED,
                               __HIP_MEMORY_SCOPE_AGENT) < 32u)
        __builtin_amdgcn_s_sleep(1);
    }
    __syncthreads();                           // (A) seq(t) staged; bar result published

    if (t > 0) {                               // stage h(t-1): 32 x 1KB rows
      const char* gh = ghb + ((size_t)(t-1)*B_ + b0)*1024;
      #pragma unroll
      for (int i = 0; i < 8; ++i) {
        int c = w*8 + i;
        dma16(gh + c*1024 + lane*16, lhc + c*1024);
      }
    }

    // seq-part MFMAs (overlap h DMA)
    f32x4 a0 = {0.f,0.f,0.f,0.f}, a1 = a0;
    WSEQ(MFS)

    if (t > 0) {
      __syncthreads();                         // (B) h DMA drained (all waves)
      WHP(MFH)
    }
    __syncthreads();                           // (C) lh reads done -> gl overlay safe

    // gates -> gl (D layout: row = 4*lhi + r, col = l16; tiles m0 at rows 0..15, m1 at 16..31)
    #pragma unroll
    for (int r = 0; r < 4; ++r) {
      gl[     lhi*4 + r][w*16 + l16] = a0[r];
      gl[16 + lhi*4 + r][w*16 + l16] = a1[r];
    }
    __syncthreads();                           // (D)

    // cell update: 2 hidden units per thread
    {
      f32x4 ga = *(const f32x4*)(&gl[crow][u2*8 + 0]);
      f32x4 gb = *(const f32x4*)(&gl[crow][u2*8 + 4]);
      float iv0 = sigm(ga[0]+biaA[0]), fv0 = sigm(ga[1]+biaA[1]);
      float gv0 = tanhf_(ga[2]+biaA[2]), ov0 = sigm(ga[3]+biaA[3]);
      cc0 = fv0*cc0 + iv0*gv0;
      float h0 = ov0*tanhf_(cc0);
      float iv1 = sigm(gb[0]+biaB[0]), fv1 = sigm(gb[1]+biaB[1]);
      float gv1 = tanhf_(gb[2]+biaB[2]), ov1 = sigm(gb[3]+biaB[3]);
      cc1 = fv1*cc1 + iv1*gv1;
      float h1 = ov1*tanhf_(cc1);
      unsigned int d0;
      asm("v_cvt_pk_bf16_f32 %0, %1, %2" : "=v"(d0) : "v"(h0), "v"(h1));
      short* dst = (short*)hb + ((size_t)t*B_ + hrow)*H_ + hoff;
      asm volatile("global_store_dword %0, %1, off sc0 sc1"
                   :: "v"(dst), "v"(d0) : "memory");
    }
    __syncthreads();                           // (E) stores drained; lseq/gl free

    if (t < T_ - 1) {
      if (tid == 0)
        __hip_atomic_fetch_add(&bar[t*16 + rg], 1u, __ATOMIC_RELAXED,
                               __HIP_MEMORY_SCOPE_AGENT);
      const char* gs = gseq + ((size_t)(t+1)*B_ + b0)*640;
      #pragma unroll
      for (int i = 0; i < 5; ++i) {            // prefetch seq(t+1) under next poll
        int c = w*5 + i;
        dma16(gs + c*1024 + lane*16, lsc + c*1024);
      }
    }
  }
}

// ============ BN1 partial stats over (B,H) per t — order-independent, swizzle-agnostic ============
__global__ __launch_bounds__(256) void k_bn1part(
    const __hip_bfloat16* __restrict__ hb, float* __restrict__ bn1s, float* __restrict__ bn1q)
{
  const int t = blockIdx.x, ch = blockIdx.y, tid = threadIdx.x;
  const short* base = (const short*)hb + ((size_t)t*B_ + ch*64)*H_;
  float s = 0.f, q = 0.f;
  for (int i = tid; i < 64*H_/8; i += 256) {
    short8 v8 = *(const short8*)(base + (i>>6)*H_ + (i&63)*8);
    #pragma unroll
    for (int j = 0; j < 8; ++j) { float v = b2f(v8[j]); s += v; q += v*v; }
  }
  __shared__ float rs[256], rq[256];
  rs[tid] = s; rq[tid] = q;
  __syncthreads();
  for (int o = 128; o; o >>= 1) {
    if (tid < o) { rs[tid] += rs[tid+o]; rq[tid] += rq[tid+o]; }
    __syncthreads();
  }
  if (tid == 0) { bn1s[t*8 + ch] = rs[0]; bn1q[t*8 + ch] = rq[0]; }
}

// ============ head: fold BN1 + (B, T*H) @ Wl^T + bl — unswizzles hbuf slots ============
__global__ __launch_bounds__(256) void k_head(
    const __hip_bfloat16* __restrict__ hb, const float* __restrict__ bn1s,
    const float* __restrict__ bn1q, const float* __restrict__ g1,
    const float* __restrict__ be1, const float* __restrict__ Wl,
    const float* __restrict__ bl, float* __restrict__ out)
{
  const int b = blockIdx.x, tid = threadIdx.x;
  __shared__ float al1[T_], bt1[T_];
  if (tid < T_) {
    float s = 0.f, q = 0.f;
    #pragma unroll
    for (int ch = 0; ch < 8; ++ch) { s += bn1s[tid*8 + ch]; q += bn1q[tid*8 + ch]; }
    const float cnt = (float)(B_*H_);
    float mu = s / cnt, var = q / cnt - mu*mu;
    float al = g1[tid] * rsqrtf(var + EPS_);
    al1[tid] = al; bt1[tid] = be1[tid] - mu*al;
  }
  __syncthreads();
  float a0 = 0.f, a1 = 0.f, a2 = 0.f;
  const short* hbs = (const short*)hb;
  for (int p8 = tid; p8 < T_*(H_/8); p8 += 256) {
    const int t = p8 >> 6, p = p8 & 63;
    short8 v8 = *(const short8*)(hbs + ((size_t)t*B_ + b)*H_ + p*8);
    const int wi = t*H_ + ((p ^ (b & 7)) << 3);    // unswizzled logical base
    #pragma unroll
    for (int j = 0; j < 8; ++j) {
      float yn = b2f(v8[j])*al1[t] + bt1[t];
      a0 = fmaf(yn, Wl[wi + j],            a0);
      a1 = fmaf(yn, Wl[T_*H_ + wi + j],    a1);
      a2 = fmaf(yn, Wl[2*T_*H_ + wi + j],  a2);
    }
  }
  __shared__ float red[256];
  red[tid] = a0; __syncthreads();
  for (int o = 128; o; o >>= 1) { if (tid < o) red[tid] += red[tid+o]; __syncthreads(); }
  if (!tid) out[b*3 + 0] = red[0] + bl[0];
  __syncthreads();
  red[tid] = a1; __syncthreads();
  for (int o = 128; o; o >>= 1) { if (tid < o) red[tid] += red[tid+o]; __syncthreads(); }
  if (!tid) out[b*3 + 1] = red[0] + bl[1];
  __syncthreads();
  red[tid] = a2; __syncthreads();
  for (int o = 128; o; o >>= 1) { if (tid < o) red[tid] += red[tid+o]; __syncthreads(); }
  if (!tid) out[b*3 + 2] = red[0] + bl[2];
}

extern "C" void kernel_launch(void* const* d_in, const int* in_sizes, int n_in,
                              void* d_out, int out_size, void* d_ws, size_t ws_size,
                              hipStream_t stream)
{
  (void)in_sizes; (void)n_in; (void)out_size;
  const float* x   = (const float*)d_in[0];
  const int* esrc  = (const int*)d_in[1];
  const int* edst  = (const int*)d_in[2];
  const float* ew  = (const float*)d_in[3];
  const float* Wc  = (const float*)d_in[4];
  const float* bc  = (const float*)d_in[5];
  const float* bng = (const float*)d_in[6];
  const float* bnb = (const float*)d_in[7];
  const float* Wih = (const float*)d_in[8];
  const float* Whh = (const float*)d_in[9];
  const float* bih = (const float*)d_in[10];
  const float* bhh = (const float*)d_in[11];
  const float* g1  = (const float*)d_in[12];
  const float* be1 = (const float*)d_in[13];
  const float* Wl  = (const float*)d_in[14];
  const float* bl  = (const float*)d_in[15];
  float* out = (float*)d_out;

  char* ws = (char*)d_ws;
  size_t off = 0;
  auto alloc = [&](size_t bytes) {
    void* p = ws + off;
    off += (bytes + 255) & ~(size_t)255;
    return p;
  };
  float* cheb = (float*)alloc(sizeof(float)*(size_t)T_*B_*NF_);
  float* bps  = (float*)alloc(sizeof(float)*T_*F_*B_);
  float* bpq  = (float*)alloc(sizeof(float)*T_*F_*B_);
  float* alpha= (float*)alloc(sizeof(float)*T_*F_);
  float* bet  = (float*)alloc(sizeof(float)*T_*F_);
  __hip_bfloat16* seqb = (__hip_bfloat16*)alloc(sizeof(__hip_bfloat16)*(size_t)T_*B_*SEQP);
  __hip_bfloat16* Wcat = (__hip_bfloat16*)alloc(sizeof(__hip_bfloat16)*(size_t)G4*KPAD);
  float* biasr = (float*)alloc(sizeof(float)*G4);
  __hip_bfloat16* hbuf = (__hip_bfloat16*)alloc(sizeof(__hip_bfloat16)*(size_t)T_*B_*H_);
  float* bn1s = (float*)alloc(sizeof(float)*T_*8);
  float* bn1q = (float*)alloc(sizeof(float)*T_*8);
  unsigned int* bar = (unsigned int*)alloc(sizeof(unsigned int)*T_*16);
  if (ws_size < off) return;   // ~76 MB — within proven budget

  (void)hipMemsetAsync(bar, 0, sizeof(unsigned int)*T_*16, stream);

  k_cheb<<<dim3(B_, T_/TC), 512, 0, stream>>>(x, esrc, edst, ew, Wc, bc, cheb, bps, bpq);
  k_bnfin<<<T_*F_, 64, 0, stream>>>(bps, bpq, bng, bnb, alpha, bet);
  k_seq<<<(T_*B_*SEQP)/256, 256, 0, stream>>>(cheb, alpha, bet, seqb);
  k_prep<<<G4, 256, 0, stream>>>(Wih, Whh, bih, bhh, Wcat, biasr);

  k_lstm<<<512, 256, 0, stream>>>(seqb, Wcat, biasr, hbuf, bar);

  k_bn1part<<<dim3(T_, 8), 256, 0, stream>>>(hbuf, bn1s, bn1q);
  k_head<<<B_, 256, 0, stream>>>(hbuf, bn1s, bn1q, g1, be1, Wl, bl, out);
}

// Round 10
// 278.349 us; speedup vs baseline: 8.6420x; 1.2312x over previous
//
#include <hip/hip_runtime.h>
#include <hip/hip_bf16.h>
#include <cstdint>

#define B_ 512
#define T_ 48
#define N_ 62
#define F_ 5
#define E_ 496
#define H_ 512
#define NF_ 310      // N*F
#define SEQP 320     // padded seq row (310 -> 320)
#define KPAD 832     // 320 + 512
#define G4 2048      // 4*H
#define EPS_ 1e-5f
#define TC 12        // t-steps per cheb block (4 chunks)
#define LSTR 72      // LDS row stride in shorts

typedef __attribute__((ext_vector_type(8))) short short8;
typedef __attribute__((ext_vector_type(4))) short s16x4;
typedef __attribute__((ext_vector_type(4))) float f32x4;

__device__ __forceinline__ float sigm(float x)  { return 1.f / (1.f + __expf(-x)); }
__device__ __forceinline__ float tanhf_(float x){ return 2.f / (1.f + __expf(-2.f*x)) - 1.f; }

__device__ __forceinline__ short f2b(float v) {   // f32 -> bf16 bits, RN-even
  unsigned int u = __builtin_bit_cast(unsigned int, v);
  unsigned int r = (u + 0x7fffu + ((u >> 16) & 1u)) >> 16;
  return (short)r;
}
__device__ __forceinline__ float b2f(short s) {
  unsigned int u = ((unsigned int)(unsigned short)s) << 16;
  return __builtin_bit_cast(float, u);
}

__device__ __forceinline__ void dma16(const void* g, void* l) {
  __builtin_amdgcn_global_load_lds(
      (const __attribute__((address_space(1))) unsigned int*)g,
      (__attribute__((address_space(3))) unsigned int*)l, 16, 0, 0);
}

// ============ ChebConv K=3 via MFMA + BN partial stats; block = (graph, 12-t chunk) ============
__global__ __launch_bounds__(512) void k_cheb(
    const float* __restrict__ x, const int* __restrict__ esrc, const int* __restrict__ edst,
    const float* __restrict__ ew, const float* __restrict__ Wc, const float* __restrict__ bc,
    float* __restrict__ cheb, float* __restrict__ bps, float* __restrict__ bpq)
{
  __shared__ __align__(16) short SH[4*64*LSTR];
  __shared__ float dinv[N_];
  short* Lb  = SH;
  short* Xt  = SH + 64*LSTR;
  short* T1t = SH + 2*64*LSTR;
  short* T2t = SH + 3*64*LSTR;
  float* Af  = (float*)T1t;

  const int tid = threadIdx.x;
  const int b = blockIdx.x;
  const int t0 = blockIdx.y * TC;

  for (int i = tid; i < 2*64*LSTR; i += 512) SH[i] = 0;
  for (int i = tid; i < N_*N_;     i += 512) Af[i] = 0.f;
  __syncthreads();

  for (int e = tid; e < E_; e += 512)
    atomicAdd(&Af[edst[b*E_ + e]*N_ + esrc[b*E_ + e]], ew[b*E_ + e]);
  for (int i = tid; i < TC*NF_; i += 512) {
    int tl = i / NF_, nf = i - tl*NF_;
    float v = x[((size_t)b*T_ + t0 + tl)*NF_ + nf];
    int n = nf / F_, f = nf - n*F_;
    Xt[(tl*F_ + f)*LSTR + n] = f2b(v);
  }
  __syncthreads();

  if (tid < N_) {
    float s = 0.f;
    for (int m = 0; m < N_; ++m) s += Af[tid*N_ + m];
    dinv[tid] = (s > 0.f) ? rsqrtf(s) : 0.f;
  }
  __syncthreads();
  for (int i = tid; i < N_*N_; i += 512) {
    int n = i / N_, m = i - n*N_;
    Lb[n*LSTR + m] = f2b(-dinv[n] * Af[i] * dinv[m]);
  }
  __syncthreads();

  const int w = tid >> 6, lane = tid & 63, l16 = lane & 15, lhi = lane >> 4;
  const int mt = w >> 1;
  const int nt = (w & 1) * 2;

  {
    f32x4 acc0 = {0.f,0.f,0.f,0.f}, acc1 = acc0;
    #pragma unroll
    for (int kc = 0; kc < 2; ++kc) {
      short8 a  = *(const short8*)(Lb + (mt*16 + l16)*LSTR + kc*32 + lhi*8);
      short8 b0 = *(const short8*)(Xt + ((nt  )*16 + l16)*LSTR + kc*32 + lhi*8);
      short8 b1 = *(const short8*)(Xt + ((nt+1)*16 + l16)*LSTR + kc*32 + lhi*8);
      acc0 = __builtin_amdgcn_mfma_f32_16x16x32_bf16(a, b0, acc0, 0, 0, 0);
      acc1 = __builtin_amdgcn_mfma_f32_16x16x32_bf16(a, b1, acc1, 0, 0, 0);
    }
    #pragma unroll
    for (int i = 0; i < 2; ++i) {
      f32x4 acc = i ? acc1 : acc0;
      int c = (nt+i)*16 + l16, n = mt*16 + lhi*4;
      s16x4 pk;
      #pragma unroll
      for (int r = 0; r < 4; ++r) pk[r] = f2b(acc[r]);
      *(s16x4*)(T1t + c*LSTR + n) = pk;
    }
  }
  __syncthreads();

  {
    f32x4 acc0 = {0.f,0.f,0.f,0.f}, acc1 = acc0;
    #pragma unroll
    for (int kc = 0; kc < 2; ++kc) {
      short8 a  = *(const short8*)(Lb + (mt*16 + l16)*LSTR + kc*32 + lhi*8);
      short8 b0 = *(const short8*)(T1t + ((nt  )*16 + l16)*LSTR + kc*32 + lhi*8);
      short8 b1 = *(const short8*)(T1t + ((nt+1)*16 + l16)*LSTR + kc*32 + lhi*8);
      acc0 = __builtin_amdgcn_mfma_f32_16x16x32_bf16(a, b0, acc0, 0, 0, 0);
      acc1 = __builtin_amdgcn_mfma_f32_16x16x32_bf16(a, b1, acc1, 0, 0, 0);
    }
    #pragma unroll
    for (int i = 0; i < 2; ++i) {
      f32x4 acc = i ? acc1 : acc0;
      int c = (nt+i)*16 + l16, n = mt*16 + lhi*4;
      s16x4 xv = *(const s16x4*)(Xt + c*LSTR + n);
      s16x4 pk;
      #pragma unroll
      for (int r = 0; r < 4; ++r) pk[r] = f2b(2.f*acc[r] - b2f(xv[r]));
      *(s16x4*)(T2t + c*LSTR + n) = pk;
    }
  }
  __syncthreads();

  const int pair = tid >> 2, q = tid & 3;
  if (pair < TC*F_) {
    const int tl = pair / F_, g = pair - (pair/F_)*F_;
    const int t = t0 + tl;
    float w0[5], w1[5], w2[5];
    #pragma unroll
    for (int ff = 0; ff < 5; ++ff) {
      w0[ff] = Wc[t*75 +      ff*5 + g];
      w1[ff] = Wc[t*75 + 25 + ff*5 + g];
      w2[ff] = Wc[t*75 + 50 + ff*5 + g];
    }
    const float bias = bc[t*F_ + g];
    float ss = 0.f, qq = 0.f;
    float* chout = cheb + ((size_t)t*B_ + b)*NF_;
    #pragma unroll
    for (int grp = 0; grp < 4; ++grp) {
      int n4 = grp*16 + q*4;
      float o[4] = {bias, bias, bias, bias};
      #pragma unroll
      for (int ff = 0; ff < 5; ++ff) {
        int c = tl*F_ + ff;
        s16x4 xv = *(const s16x4*)(Xt  + c*LSTR + n4);
        s16x4 v1 = *(const s16x4*)(T1t + c*LSTR + n4);
        s16x4 v2 = *(const s16x4*)(T2t + c*LSTR + n4);
        #pragma unroll
        for (int i = 0; i < 4; ++i)
          o[i] += b2f(xv[i])*w0[ff] + b2f(v1[i])*w1[ff] + b2f(v2[i])*w2[ff];
      }
      #pragma unroll
      for (int i = 0; i < 4; ++i) {
        int n = n4 + i;
        if (n < N_) { chout[n*F_ + g] = o[i]; ss += o[i]; qq += o[i]*o[i]; }
      }
    }
    ss += __shfl_down(ss, 2, 4); ss += __shfl_down(ss, 1, 4);
    qq += __shfl_down(qq, 2, 4); qq += __shfl_down(qq, 1, 4);
    if (q == 0) { bps[(t*F_ + g)*B_ + b] = ss; bpq[(t*F_ + g)*B_ + b] = qq; }
  }
}

// ============ finalize BN scale/shift per (t,f) ============
__global__ __launch_bounds__(64) void k_bnfin(
    const float* __restrict__ bps, const float* __restrict__ bpq,
    const float* __restrict__ bng, const float* __restrict__ bnb,
    float* __restrict__ alpha, float* __restrict__ bet)
{
  const int tf = blockIdx.x;
  const int lane = threadIdx.x;
  float s = 0.f, q = 0.f;
  for (int i = lane; i < B_; i += 64) { s += bps[tf*B_ + i]; q += bpq[tf*B_ + i]; }
  #pragma unroll
  for (int off = 32; off; off >>= 1) { s += __shfl_down(s, off); q += __shfl_down(q, off); }
  if (lane == 0) {
    const float cnt = (float)(B_*N_);
    float mu = s / cnt;
    float var = q / cnt - mu*mu;
    float al = bng[tf] * rsqrtf(var + EPS_);
    alpha[tf] = al;
    bet[tf] = bnb[tf] - mu*al;
  }
}

// ============ BN apply + pack to bf16 PRE-SWIZZLED sequence [t][b][320] ============
__global__ __launch_bounds__(256) void k_seq(
    const float* __restrict__ cheb, const float* __restrict__ alpha, const float* __restrict__ bet,
    __hip_bfloat16* __restrict__ seqb)
{
  int idx = blockIdx.x*256 + threadIdx.x;     // T*B*320
  int kp = idx % SEQP;                        // physical position
  int tb = idx / SEQP;
  int b = tb & (B_-1), t = tb >> 9;
  int sl = (kp >> 3) ^ (b & 7);               // logical slot
  int kl = sl*8 + (kp & 7);                   // logical element
  float v = 0.f;
  if (kl < NF_) v = cheb[(size_t)tb*NF_ + kl] * alpha[t*F_ + (kl % F_)] + bet[t*F_ + (kl % F_)];
  seqb[idx] = __float2bfloat16(v);
}

// ============ weight prep: gate-interleaved rows j' = jh*4 + gate; K = [seq-logical|pad|h] ============
__global__ __launch_bounds__(256) void k_prep(
    const float* __restrict__ Wih, const float* __restrict__ Whh,
    const float* __restrict__ bih, const float* __restrict__ bhh,
    __hip_bfloat16* __restrict__ Wcat, float* __restrict__ biasr)
{
  const int jp = blockIdx.x;
  const int g = jp & 3, jh = jp >> 2;
  const int jo = g*H_ + jh;
  for (int k = threadIdx.x; k < KPAD; k += 256) {
    float v = 0.f;
    if (k < NF_) v = Wih[(size_t)jo*NF_ + k];
    else if (k >= SEQP) v = Whh[(size_t)jo*H_ + (k - SEQP)];
    Wcat[(size_t)jp*KPAD + k] = __float2bfloat16(v);
  }
  if (threadIdx.x == 0) biasr[jp] = bih[jo] + bhh[jo];
}

// ============ persistent LSTM v5: LDS-DMA panels, VGPR weights, decontended flags ============
// 512 blocks x 256 thr (2 blocks/CU). Block (rg=bid&15, jt=bid>>4): 32 b-rows x 64 j'-cols.
// bar is RG-MAJOR (bar[rg*64 + t]) so each group's flags live in their own cachelines —
// per line per step: 32 adds + 32 pollers (was 512+512 on one line = the round-9 stall).
#define WOP(M)  M(0) M(1) M(2) M(3) M(4) M(5) M(6) M(7) M(8) M(9) M(10) M(11) M(12) M(13) \
                M(14) M(15) M(16) M(17) M(18) M(19) M(20) M(21) M(22) M(23) M(24) M(25)
#define WSEQ(M) M(0) M(1) M(2) M(3) M(4) M(5) M(6) M(7) M(8) M(9)
#define WHP(M)  M(10) M(11) M(12) M(13) M(14) M(15) M(16) M(17) M(18) M(19) M(20) M(21) \
                M(22) M(23) M(24) M(25)

#define DECLW(i) short8 wv##i;
#define LOADW(i) wv##i = *(const short8*)(wp + (i)*32); \
                 asm volatile("" : "+v"(wv##i));
#define MFS(i) { const int ph = (((i)*4 + lhi) ^ key)*8; \
                 short8 x0 = *(const short8*)(lseq + rs0*SEQP + ph); \
                 short8 x1 = *(const short8*)(lseq + rs1*SEQP + ph); \
                 a0 = __builtin_amdgcn_mfma_f32_16x16x32_bf16(x0, wv##i, a0, 0, 0, 0); \
                 a1 = __builtin_amdgcn_mfma_f32_16x16x32_bf16(x1, wv##i, a1, 0, 0, 0); }
#define MFH(i) { const int ph = ((((i)-10)*4 + lhi) ^ key)*8; \
                 short8 x0 = *(const short8*)(lh + rs0*H_ + ph); \
                 short8 x1 = *(const short8*)(lh + rs1*H_ + ph); \
                 a0 = __builtin_amdgcn_mfma_f32_16x16x32_bf16(x0, wv##i, a0, 0, 0, 0); \
                 a1 = __builtin_amdgcn_mfma_f32_16x16x32_bf16(x1, wv##i, a1, 0, 0, 0); }

__global__ __launch_bounds__(256, 2) void k_lstm(
    const __hip_bfloat16* __restrict__ seqb,   // (T, B, 320) bf16, slot-swizzled
    const __hip_bfloat16* __restrict__ Wcat,   // (2048, 832) gate-interleaved
    const float* __restrict__ biasr,           // (2048)
    __hip_bfloat16* __restrict__ hb,           // (T, B, 512) bf16, slot-swizzled, write-once
    unsigned int* __restrict__ bar)            // (16*64) zeroed, rg-major
{
  __shared__ __align__(16) short lh[32*H_];    // 32 KB: h panel (overlaid by gl after WHP)
  __shared__ __align__(16) short lseq[32*SEQP];// 20 KB: seq panel
  float (*gl)[68] = (float (*)[68])lh;         // 32x68 f32 = 8.7 KB overlay

  const int tid = threadIdx.x;
  const int bid = blockIdx.x;
  const int rg = bid & 15, jt = bid >> 4;
  const int b0 = rg*32, j0 = jt*64;
  const int w = tid >> 6, lane = tid & 63, l16 = lane & 15, lhi = lane >> 4;
  const int key = l16 & 7;
  const int rs0 = l16, rs1 = l16 + 16;

  // ---- pin this wave's 26 weight fragments (col-tile nt = w) ----
  const short* wp = (const short*)Wcat + (size_t)(j0 + w*16 + l16)*KPAD + lhi*8;
  WOP(DECLW)
  WOP(LOADW)

  const int crow = tid >> 3, u2 = tid & 7;
  const int hrow = b0 + crow;
  float cc0 = 0.f, cc1 = 0.f;
  f32x4 biaA = *(const f32x4*)(biasr + j0 + u2*8 + 0);
  f32x4 biaB = *(const f32x4*)(biasr + j0 + u2*8 + 4);
  const int hslot = (jt*2 + (u2 >> 2)) ^ (hrow & 7);
  const int hoff = hslot*8 + (u2 & 3)*2;

  const char* gseq = (const char*)seqb;
  const char* ghb  = (const char*)hb;
  char* lsc = (char*)lseq;
  char* lhc = (char*)lh;

  // prologue: stage seq(0)
  {
    const char* gs = gseq + ((size_t)b0)*640;
    #pragma unroll
    for (int i = 0; i < 5; ++i) {
      int c = w*5 + i;
      dma16(gs + c*1024 + lane*16, lsc + c*1024);
    }
  }

  #pragma unroll 1
  for (int t = 0; t < T_; ++t) {
    if (t > 0 && tid == 0) {
      while (__hip_atomic_load(&bar[rg*64 + (t-1)], __ATOMIC_RELAXED,
                               __HIP_MEMORY_SCOPE_AGENT) < 32u)
        __builtin_amdgcn_s_sleep(2);
    }
    __syncthreads();                           // (A) seq(t) staged; flag seen

    if (t > 0) {                               // stage h(t-1): 32 x 1KB rows
      const char* gh = ghb + ((size_t)(t-1)*B_ + b0)*1024;
      #pragma unroll
      for (int i = 0; i < 8; ++i) {
        int c = w*8 + i;
        dma16(gh + c*1024 + lane*16, lhc + c*1024);
      }
    }

    // seq-part MFMAs (overlap h DMA)
    f32x4 a0 = {0.f,0.f,0.f,0.f}, a1 = a0;
    WSEQ(MFS)

    if (t > 0) {
      __syncthreads();                         // (B) h DMA drained (all waves)
      WHP(MFH)
    }
    __syncthreads();                           // (C) lh reads done -> gl overlay safe

    #pragma unroll
    for (int r = 0; r < 4; ++r) {
      gl[     lhi*4 + r][w*16 + l16] = a0[r];
      gl[16 + lhi*4 + r][w*16 + l16] = a1[r];
    }
    __syncthreads();                           // (D)

    // cell update: 2 hidden units per thread
    {
      f32x4 ga = *(const f32x4*)(&gl[crow][u2*8 + 0]);
      f32x4 gb = *(const f32x4*)(&gl[crow][u2*8 + 4]);
      float iv0 = sigm(ga[0]+biaA[0]), fv0 = sigm(ga[1]+biaA[1]);
      float gv0 = tanhf_(ga[2]+biaA[2]), ov0 = sigm(ga[3]+biaA[3]);
      cc0 = fv0*cc0 + iv0*gv0;
      float h0 = ov0*tanhf_(cc0);
      float iv1 = sigm(gb[0]+biaB[0]), fv1 = sigm(gb[1]+biaB[1]);
      float gv1 = tanhf_(gb[2]+biaB[2]), ov1 = sigm(gb[3]+biaB[3]);
      cc1 = fv1*cc1 + iv1*gv1;
      float h1 = ov1*tanhf_(cc1);
      unsigned int d0;
      asm("v_cvt_pk_bf16_f32 %0, %1, %2" : "=v"(d0) : "v"(h0), "v"(h1));
      short* dst = (short*)hb + ((size_t)t*B_ + hrow)*H_ + hoff;
      asm volatile("global_store_dword %0, %1, off sc0 sc1"
                   :: "v"(dst), "v"(d0) : "memory");
    }

    if (t < T_ - 1) {                          // prefetch seq(t+1) UNDER the store drain
      const char* gs = gseq + ((size_t)(t+1)*B_ + b0)*640;
      #pragma unroll
      for (int i = 0; i < 5; ++i) {
        int c = w*5 + i;
        dma16(gs + c*1024 + lane*16, lsc + c*1024);
      }
    }
    __syncthreads();                           // (E) stores + prefetch drained

    if (t < T_ - 1 && tid == 0)
      __hip_atomic_fetch_add(&bar[rg*64 + t], 1u, __ATOMIC_RELAXED,
                             __HIP_MEMORY_SCOPE_AGENT);
  }
}

// ============ BN1 partial stats over (B,H) per t — order-independent, swizzle-agnostic ============
__global__ __launch_bounds__(256) void k_bn1part(
    const __hip_bfloat16* __restrict__ hb, float* __restrict__ bn1s, float* __restrict__ bn1q)
{
  const int t = blockIdx.x, ch = blockIdx.y, tid = threadIdx.x;
  const short* base = (const short*)hb + ((size_t)t*B_ + ch*64)*H_;
  float s = 0.f, q = 0.f;
  for (int i = tid; i < 64*H_/8; i += 256) {
    short8 v8 = *(const short8*)(base + (i>>6)*H_ + (i&63)*8);
    #pragma unroll
    for (int j = 0; j < 8; ++j) { float v = b2f(v8[j]); s += v; q += v*v; }
  }
  __shared__ float rs[256], rq[256];
  rs[tid] = s; rq[tid] = q;
  __syncthreads();
  for (int o = 128; o; o >>= 1) {
    if (tid < o) { rs[tid] += rs[tid+o]; rq[tid] += rq[tid+o]; }
    __syncthreads();
  }
  if (tid == 0) { bn1s[t*8 + ch] = rs[0]; bn1q[t*8 + ch] = rq[0]; }
}

// ============ head: fold BN1 + (B, T*H) @ Wl^T + bl — unswizzles hbuf slots ============
__global__ __launch_bounds__(256) void k_head(
    const __hip_bfloat16* __restrict__ hb, const float* __restrict__ bn1s,
    const float* __restrict__ bn1q, const float* __restrict__ g1,
    const float* __restrict__ be1, const float* __restrict__ Wl,
    const float* __restrict__ bl, float* __restrict__ out)
{
  const int b = blockIdx.x, tid = threadIdx.x;
  __shared__ float al1[T_], bt1[T_];
  if (tid < T_) {
    float s = 0.f, q = 0.f;
    #pragma unroll
    for (int ch = 0; ch < 8; ++ch) { s += bn1s[tid*8 + ch]; q += bn1q[tid*8 + ch]; }
    const float cnt = (float)(B_*H_);
    float mu = s / cnt, var = q / cnt - mu*mu;
    float al = g1[tid] * rsqrtf(var + EPS_);
    al1[tid] = al; bt1[tid] = be1[tid] - mu*al;
  }
  __syncthreads();
  float a0 = 0.f, a1 = 0.f, a2 = 0.f;
  const short* hbs = (const short*)hb;
  for (int p8 = tid; p8 < T_*(H_/8); p8 += 256) {
    const int t = p8 >> 6, p = p8 & 63;
    short8 v8 = *(const short8*)(hbs + ((size_t)t*B_ + b)*H_ + p*8);
    const int wi = t*H_ + ((p ^ (b & 7)) << 3);
    #pragma unroll
    for (int j = 0; j < 8; ++j) {
      float yn = b2f(v8[j])*al1[t] + bt1[t];
      a0 = fmaf(yn, Wl[wi + j],            a0);
      a1 = fmaf(yn, Wl[T_*H_ + wi + j],    a1);
      a2 = fmaf(yn, Wl[2*T_*H_ + wi + j],  a2);
    }
  }
  __shared__ float red[256];
  red[tid] = a0; __syncthreads();
  for (int o = 128; o; o >>= 1) { if (tid < o) red[tid] += red[tid+o]; __syncthreads(); }
  if (!tid) out[b*3 + 0] = red[0] + bl[0];
  __syncthreads();
  red[tid] = a1; __syncthreads();
  for (int o = 128; o; o >>= 1) { if (tid < o) red[tid] += red[tid+o]; __syncthreads(); }
  if (!tid) out[b*3 + 1] = red[0] + bl[1];
  __syncthreads();
  red[tid] = a2; __syncthreads();
  for (int o = 128; o; o >>= 1) { if (tid < o) red[tid] += red[tid+o]; __syncthreads(); }
  if (!tid) out[b*3 + 2] = red[0] + bl[2];
}

extern "C" void kernel_launch(void* const* d_in, const int* in_sizes, int n_in,
                              void* d_out, int out_size, void* d_ws, size_t ws_size,
                              hipStream_t stream)
{
  (void)in_sizes; (void)n_in; (void)out_size;
  const float* x   = (const float*)d_in[0];
  const int* esrc  = (const int*)d_in[1];
  const int* edst  = (const int*)d_in[2];
  const float* ew  = (const float*)d_in[3];
  const float* Wc  = (const float*)d_in[4];
  const float* bc  = (const float*)d_in[5];
  const float* bng = (const float*)d_in[6];
  const float* bnb = (const float*)d_in[7];
  const float* Wih = (const float*)d_in[8];
  const float* Whh = (const float*)d_in[9];
  const float* bih = (const float*)d_in[10];
  const float* bhh = (const float*)d_in[11];
  const float* g1  = (const float*)d_in[12];
  const float* be1 = (const float*)d_in[13];
  const float* Wl  = (const float*)d_in[14];
  const float* bl  = (const float*)d_in[15];
  float* out = (float*)d_out;

  char* ws = (char*)d_ws;
  size_t off = 0;
  auto alloc = [&](size_t bytes) {
    void* p = ws + off;
    off += (bytes + 255) & ~(size_t)255;
    return p;
  };
  float* cheb = (float*)alloc(sizeof(float)*(size_t)T_*B_*NF_);
  float* bps  = (float*)alloc(sizeof(float)*T_*F_*B_);
  float* bpq  = (float*)alloc(sizeof(float)*T_*F_*B_);
  float* alpha= (float*)alloc(sizeof(float)*T_*F_);
  float* bet  = (float*)alloc(sizeof(float)*T_*F_);
  __hip_bfloat16* seqb = (__hip_bfloat16*)alloc(sizeof(__hip_bfloat16)*(size_t)T_*B_*SEQP);
  __hip_bfloat16* Wcat = (__hip_bfloat16*)alloc(sizeof(__hip_bfloat16)*(size_t)G4*KPAD);
  float* biasr = (float*)alloc(sizeof(float)*G4);
  __hip_bfloat16* hbuf = (__hip_bfloat16*)alloc(sizeof(__hip_bfloat16)*(size_t)T_*B_*H_);
  float* bn1s = (float*)alloc(sizeof(float)*T_*8);
  float* bn1q = (float*)alloc(sizeof(float)*T_*8);
  unsigned int* bar = (unsigned int*)alloc(sizeof(unsigned int)*16*64);
  if (ws_size < off) return;   // ~76 MB — within proven budget

  (void)hipMemsetAsync(bar, 0, sizeof(unsigned int)*16*64, stream);

  k_cheb<<<dim3(B_, T_/TC), 512, 0, stream>>>(x, esrc, edst, ew, Wc, bc, cheb, bps, bpq);
  k_bnfin<<<T_*F_, 64, 0, stream>>>(bps, bpq, bng, bnb, alpha, bet);
  k_seq<<<(T_*B_*SEQP)/256, 256, 0, stream>>>(cheb, alpha, bet, seqb);
  k_prep<<<G4, 256, 0, stream>>>(Wih, Whh, bih, bhh, Wcat, biasr);

  k_lstm<<<512, 256, 0, stream>>>(seqb, Wcat, biasr, hbuf, bar);

  k_bn1part<<<dim3(T_, 8), 256, 0, stream>>>(hbuf, bn1s, bn1q);
  k_head<<<B_, 256, 0, stream>>>(hbuf, bn1s, bn1q, g1, be1, Wl, bl, out);
}

// Round 11
// 274.886 us; speedup vs baseline: 8.7508x; 1.0126x over previous
//
#include <hip/hip_runtime.h>
#include <hip/hip_bf16.h>
#include <cstdint>

#define B_ 512
#define T_ 48
#define N_ 62
#define F_ 5
#define E_ 496
#define H_ 512
#define NF_ 310      // N*F
#define SEQP 320     // padded seq row (310 -> 320)
#define KPAD 832     // 320 + 512
#define G4 2048      // 4*H
#define EPS_ 1e-5f
#define TC 12        // t-steps per cheb block (4 chunks)
#define LSTR 72      // LDS row stride in shorts

typedef __attribute__((ext_vector_type(8))) short short8;
typedef __attribute__((ext_vector_type(4))) short s16x4;
typedef __attribute__((ext_vector_type(4))) float f32x4;

__device__ __forceinline__ float sigm(float x)  { return 1.f / (1.f + __expf(-x)); }
__device__ __forceinline__ float tanhf_(float x){ return 2.f / (1.f + __expf(-2.f*x)) - 1.f; }

__device__ __forceinline__ short f2b(float v) {   // f32 -> bf16 bits, RN-even
  unsigned int u = __builtin_bit_cast(unsigned int, v);
  unsigned int r = (u + 0x7fffu + ((u >> 16) & 1u)) >> 16;
  return (short)r;
}
__device__ __forceinline__ float b2f(short s) {
  unsigned int u = ((unsigned int)(unsigned short)s) << 16;
  return __builtin_bit_cast(float, u);
}

__device__ __forceinline__ void dma16(const void* g, void* l) {
  __builtin_amdgcn_global_load_lds(
      (const __attribute__((address_space(1))) unsigned int*)g,
      (__attribute__((address_space(3))) unsigned int*)l, 16, 0, 0);
}

// ============ ChebConv K=3 via MFMA + BN partial stats; block = (graph, 12-t chunk) ============
__global__ __launch_bounds__(512) void k_cheb(
    const float* __restrict__ x, const int* __restrict__ esrc, const int* __restrict__ edst,
    const float* __restrict__ ew, const float* __restrict__ Wc, const float* __restrict__ bc,
    float* __restrict__ cheb, float* __restrict__ bps, float* __restrict__ bpq)
{
  __shared__ __align__(16) short SH[4*64*LSTR];
  __shared__ float dinv[N_];
  short* Lb  = SH;
  short* Xt  = SH + 64*LSTR;
  short* T1t = SH + 2*64*LSTR;
  short* T2t = SH + 3*64*LSTR;
  float* Af  = (float*)T1t;

  const int tid = threadIdx.x;
  const int b = blockIdx.x;
  const int t0 = blockIdx.y * TC;

  for (int i = tid; i < 2*64*LSTR; i += 512) SH[i] = 0;
  for (int i = tid; i < N_*N_;     i += 512) Af[i] = 0.f;
  __syncthreads();

  for (int e = tid; e < E_; e += 512)
    atomicAdd(&Af[edst[b*E_ + e]*N_ + esrc[b*E_ + e]], ew[b*E_ + e]);
  for (int i = tid; i < TC*NF_; i += 512) {
    int tl = i / NF_, nf = i - tl*NF_;
    float v = x[((size_t)b*T_ + t0 + tl)*NF_ + nf];
    int n = nf / F_, f = nf - n*F_;
    Xt[(tl*F_ + f)*LSTR + n] = f2b(v);
  }
  __syncthreads();

  if (tid < N_) {
    float s = 0.f;
    for (int m = 0; m < N_; ++m) s += Af[tid*N_ + m];
    dinv[tid] = (s > 0.f) ? rsqrtf(s) : 0.f;
  }
  __syncthreads();
  for (int i = tid; i < N_*N_; i += 512) {
    int n = i / N_, m = i - n*N_;
    Lb[n*LSTR + m] = f2b(-dinv[n] * Af[i] * dinv[m]);
  }
  __syncthreads();

  const int w = tid >> 6, lane = tid & 63, l16 = lane & 15, lhi = lane >> 4;
  const int mt = w >> 1;
  const int nt = (w & 1) * 2;

  {
    f32x4 acc0 = {0.f,0.f,0.f,0.f}, acc1 = acc0;
    #pragma unroll
    for (int kc = 0; kc < 2; ++kc) {
      short8 a  = *(const short8*)(Lb + (mt*16 + l16)*LSTR + kc*32 + lhi*8);
      short8 b0 = *(const short8*)(Xt + ((nt  )*16 + l16)*LSTR + kc*32 + lhi*8);
      short8 b1 = *(const short8*)(Xt + ((nt+1)*16 + l16)*LSTR + kc*32 + lhi*8);
      acc0 = __builtin_amdgcn_mfma_f32_16x16x32_bf16(a, b0, acc0, 0, 0, 0);
      acc1 = __builtin_amdgcn_mfma_f32_16x16x32_bf16(a, b1, acc1, 0, 0, 0);
    }
    #pragma unroll
    for (int i = 0; i < 2; ++i) {
      f32x4 acc = i ? acc1 : acc0;
      int c = (nt+i)*16 + l16, n = mt*16 + lhi*4;
      s16x4 pk;
      #pragma unroll
      for (int r = 0; r < 4; ++r) pk[r] = f2b(acc[r]);
      *(s16x4*)(T1t + c*LSTR + n) = pk;
    }
  }
  __syncthreads();

  {
    f32x4 acc0 = {0.f,0.f,0.f,0.f}, acc1 = acc0;
    #pragma unroll
    for (int kc = 0; kc < 2; ++kc) {
      short8 a  = *(const short8*)(Lb + (mt*16 + l16)*LSTR + kc*32 + lhi*8);
      short8 b0 = *(const short8*)(T1t + ((nt  )*16 + l16)*LSTR + kc*32 + lhi*8);
      short8 b1 = *(const short8*)(T1t + ((nt+1)*16 + l16)*LSTR + kc*32 + lhi*8);
      acc0 = __builtin_amdgcn_mfma_f32_16x16x32_bf16(a, b0, acc0, 0, 0, 0);
      acc1 = __builtin_amdgcn_mfma_f32_16x16x32_bf16(a, b1, acc1, 0, 0, 0);
    }
    #pragma unroll
    for (int i = 0; i < 2; ++i) {
      f32x4 acc = i ? acc1 : acc0;
      int c = (nt+i)*16 + l16, n = mt*16 + lhi*4;
      s16x4 xv = *(const s16x4*)(Xt + c*LSTR + n);
      s16x4 pk;
      #pragma unroll
      for (int r = 0; r < 4; ++r) pk[r] = f2b(2.f*acc[r] - b2f(xv[r]));
      *(s16x4*)(T2t + c*LSTR + n) = pk;
    }
  }
  __syncthreads();

  const int pair = tid >> 2, q = tid & 3;
  if (pair < TC*F_) {
    const int tl = pair / F_, g = pair - (pair/F_)*F_;
    const int t = t0 + tl;
    float w0[5], w1[5], w2[5];
    #pragma unroll
    for (int ff = 0; ff < 5; ++ff) {
      w0[ff] = Wc[t*75 +      ff*5 + g];
      w1[ff] = Wc[t*75 + 25 + ff*5 + g];
      w2[ff] = Wc[t*75 + 50 + ff*5 + g];
    }
    const float bias = bc[t*F_ + g];
    float ss = 0.f, qq = 0.f;
    float* chout = cheb + ((size_t)t*B_ + b)*NF_;
    #pragma unroll
    for (int grp = 0; grp < 4; ++grp) {
      int n4 = grp*16 + q*4;
      float o[4] = {bias, bias, bias, bias};
      #pragma unroll
      for (int ff = 0; ff < 5; ++ff) {
        int c = tl*F_ + ff;
        s16x4 xv = *(const s16x4*)(Xt  + c*LSTR + n4);
        s16x4 v1 = *(const s16x4*)(T1t + c*LSTR + n4);
        s16x4 v2 = *(const s16x4*)(T2t + c*LSTR + n4);
        #pragma unroll
        for (int i = 0; i < 4; ++i)
          o[i] += b2f(xv[i])*w0[ff] + b2f(v1[i])*w1[ff] + b2f(v2[i])*w2[ff];
      }
      #pragma unroll
      for (int i = 0; i < 4; ++i) {
        int n = n4 + i;
        if (n < N_) { chout[n*F_ + g] = o[i]; ss += o[i]; qq += o[i]*o[i]; }
      }
    }
    ss += __shfl_down(ss, 2, 4); ss += __shfl_down(ss, 1, 4);
    qq += __shfl_down(qq, 2, 4); qq += __shfl_down(qq, 1, 4);
    if (q == 0) { bps[(t*F_ + g)*B_ + b] = ss; bpq[(t*F_ + g)*B_ + b] = qq; }
  }
}

// ============ finalize BN scale/shift per (t,f) ============
__global__ __launch_bounds__(64) void k_bnfin(
    const float* __restrict__ bps, const float* __restrict__ bpq,
    const float* __restrict__ bng, const float* __restrict__ bnb,
    float* __restrict__ alpha, float* __restrict__ bet)
{
  const int tf = blockIdx.x;
  const int lane = threadIdx.x;
  float s = 0.f, q = 0.f;
  for (int i = lane; i < B_; i += 64) { s += bps[tf*B_ + i]; q += bpq[tf*B_ + i]; }
  #pragma unroll
  for (int off = 32; off; off >>= 1) { s += __shfl_down(s, off); q += __shfl_down(q, off); }
  if (lane == 0) {
    const float cnt = (float)(B_*N_);
    float mu = s / cnt;
    float var = q / cnt - mu*mu;
    float al = bng[tf] * rsqrtf(var + EPS_);
    alpha[tf] = al;
    bet[tf] = bnb[tf] - mu*al;
  }
}

// ============ BN apply + pack to bf16 PRE-SWIZZLED sequence [t][b][320] ============
__global__ __launch_bounds__(256) void k_seq(
    const float* __restrict__ cheb, const float* __restrict__ alpha, const float* __restrict__ bet,
    __hip_bfloat16* __restrict__ seqb)
{
  int idx = blockIdx.x*256 + threadIdx.x;     // T*B*320
  int kp = idx % SEQP;                        // physical position
  int tb = idx / SEQP;
  int b = tb & (B_-1), t = tb >> 9;
  int sl = (kp >> 3) ^ (b & 7);               // logical slot
  int kl = sl*8 + (kp & 7);                   // logical element
  float v = 0.f;
  if (kl < NF_) v = cheb[(size_t)tb*NF_ + kl] * alpha[t*F_ + (kl % F_)] + bet[t*F_ + (kl % F_)];
  seqb[idx] = __float2bfloat16(v);
}

// ============ weight prep: gate-interleaved rows j' = jh*4 + gate; K = [seq-logical|pad|h] ============
__global__ __launch_bounds__(256) void k_prep(
    const float* __restrict__ Wih, const float* __restrict__ Whh,
    const float* __restrict__ bih, const float* __restrict__ bhh,
    __hip_bfloat16* __restrict__ Wcat, float* __restrict__ biasr)
{
  const int jp = blockIdx.x;
  const int g = jp & 3, jh = jp >> 2;
  const int jo = g*H_ + jh;
  for (int k = threadIdx.x; k < KPAD; k += 256) {
    float v = 0.f;
    if (k < NF_) v = Wih[(size_t)jo*NF_ + k];
    else if (k >= SEQP) v = Whh[(size_t)jo*H_ + (k - SEQP)];
    Wcat[(size_t)jp*KPAD + k] = __float2bfloat16(v);
  }
  if (threadIdx.x == 0) biasr[jp] = bih[jo] + bhh[jo];
}

// ============ persistent LSTM v6: flag-vector sync, dedicated gl, off-path prefetch ============
// 512 blocks x 256 thr (2 blocks/CU). Block (rg=bid&15, jt=bid>>4): 32 b-rows x 64 j'-cols.
// Per step: producer jt plain-stores t+1 into its OWN word bar[rg*64+jt] (no RMW
// serialization); consumer wave-0 lanes 0..31 load all 32 flags in one parallel round.
#define WOP(M)  M(0) M(1) M(2) M(3) M(4) M(5) M(6) M(7) M(8) M(9) M(10) M(11) M(12) M(13) \
                M(14) M(15) M(16) M(17) M(18) M(19) M(20) M(21) M(22) M(23) M(24) M(25)
#define WSEQ(M) M(0) M(1) M(2) M(3) M(4) M(5) M(6) M(7) M(8) M(9)
#define WHP(M)  M(10) M(11) M(12) M(13) M(14) M(15) M(16) M(17) M(18) M(19) M(20) M(21) \
                M(22) M(23) M(24) M(25)

#define DECLW(i) short8 wv##i;
#define LOADW(i) wv##i = *(const short8*)(wp + (i)*32); \
                 asm volatile("" : "+v"(wv##i));
#define MFS(i) { const int ph = (((i)*4 + lhi) ^ key)*8; \
                 short8 x0 = *(const short8*)(lseq + rs0*SEQP + ph); \
                 short8 x1 = *(const short8*)(lseq + rs1*SEQP + ph); \
                 a0 = __builtin_amdgcn_mfma_f32_16x16x32_bf16(x0, wv##i, a0, 0, 0, 0); \
                 a1 = __builtin_amdgcn_mfma_f32_16x16x32_bf16(x1, wv##i, a1, 0, 0, 0); }
#define MFH(i) { const int ph = ((((i)-10)*4 + lhi) ^ key)*8; \
                 short8 x0 = *(const short8*)(lh + rs0*H_ + ph); \
                 short8 x1 = *(const short8*)(lh + rs1*H_ + ph); \
                 a0 = __builtin_amdgcn_mfma_f32_16x16x32_bf16(x0, wv##i, a0, 0, 0, 0); \
                 a1 = __builtin_amdgcn_mfma_f32_16x16x32_bf16(x1, wv##i, a1, 0, 0, 0); }

__global__ __launch_bounds__(256, 2) void k_lstm(
    const __hip_bfloat16* __restrict__ seqb,   // (T, B, 320) bf16, slot-swizzled
    const __hip_bfloat16* __restrict__ Wcat,   // (2048, 832) gate-interleaved
    const float* __restrict__ biasr,           // (2048)
    __hip_bfloat16* __restrict__ hb,           // (T, B, 512) bf16, slot-swizzled, write-once
    unsigned int* __restrict__ bar)            // (16*64) zeroed, rg-major flag words
{
  __shared__ __align__(16) short lh[32*H_];    // 32 KB: h panel
  __shared__ __align__(16) short lseq[32*SEQP];// 20 KB: seq panel
  __shared__ __align__(16) float gl[32][68];   // 8.7 KB: gate tile (own region, no overlay)

  const int tid = threadIdx.x;
  const int bid = blockIdx.x;
  const int rg = bid & 15, jt = bid >> 4;
  const int b0 = rg*32, j0 = jt*64;
  const int w = tid >> 6, lane = tid & 63, l16 = lane & 15, lhi = lane >> 4;
  const int key = l16 & 7;
  const int rs0 = l16, rs1 = l16 + 16;

  // ---- pin this wave's 26 weight fragments (col-tile nt = w) ----
  const short* wp = (const short*)Wcat + (size_t)(j0 + w*16 + l16)*KPAD + lhi*8;
  WOP(DECLW)
  WOP(LOADW)

  const int crow = tid >> 3, u2 = tid & 7;
  const int hrow = b0 + crow;
  float cc0 = 0.f, cc1 = 0.f;
  f32x4 biaA = *(const f32x4*)(biasr + j0 + u2*8 + 0);
  f32x4 biaB = *(const f32x4*)(biasr + j0 + u2*8 + 4);
  const int hslot = (jt*2 + (u2 >> 2)) ^ (hrow & 7);
  const int hoff = hslot*8 + (u2 & 3)*2;

  const char* gseq = (const char*)seqb;
  const char* ghb  = (const char*)hb;
  char* lsc = (char*)lseq;
  char* lhc = (char*)lh;

  // prologue: stage seq(0)
  {
    const char* gs = gseq + ((size_t)b0)*640;
    #pragma unroll
    for (int i = 0; i < 5; ++i) {
      int c = w*5 + i;
      dma16(gs + c*1024 + lane*16, lsc + c*1024);
    }
  }

  #pragma unroll 1
  for (int t = 0; t < T_; ++t) {
    // ---- wait for all 32 producers' flags >= t (parallel 32-lane probe) ----
    if (t > 0 && w == 0) {
      for (;;) {
        unsigned int v = 0xFFFFFFFFu;
        if (lane < 32)
          v = __hip_atomic_load(&bar[rg*64 + lane], __ATOMIC_RELAXED,
                                __HIP_MEMORY_SCOPE_AGENT);
        if (__all(v >= (unsigned int)t)) break;
        __builtin_amdgcn_s_sleep(1);
      }
    }
    __syncthreads();                           // (A) seq(t) staged; flags seen; prefetch drained

    if (t > 0) {                               // stage h(t-1): 32 x 1KB rows
      const char* gh = ghb + ((size_t)(t-1)*B_ + b0)*1024;
      #pragma unroll
      for (int i = 0; i < 8; ++i) {
        int c = w*8 + i;
        dma16(gh + c*1024 + lane*16, lhc + c*1024);
      }
    }

    // seq-part MFMAs (overlap h DMA)
    f32x4 a0 = {0.f,0.f,0.f,0.f}, a1 = a0;
    WSEQ(MFS)

    if (t > 0) {
      __syncthreads();                         // (B) h DMA drained (all waves)
      WHP(MFH)
    }

    #pragma unroll
    for (int r = 0; r < 4; ++r) {              // gl is a dedicated region: no pre-barrier needed
      gl[     lhi*4 + r][w*16 + l16] = a0[r];
      gl[16 + lhi*4 + r][w*16 + l16] = a1[r];
    }
    __syncthreads();                           // (D) gl visible

    // cell update: 2 hidden units per thread
    {
      f32x4 ga = *(const f32x4*)(&gl[crow][u2*8 + 0]);
      f32x4 gb = *(const f32x4*)(&gl[crow][u2*8 + 4]);
      float iv0 = sigm(ga[0]+biaA[0]), fv0 = sigm(ga[1]+biaA[1]);
      float gv0 = tanhf_(ga[2]+biaA[2]), ov0 = sigm(ga[3]+biaA[3]);
      cc0 = fv0*cc0 + iv0*gv0;
      float h0 = ov0*tanhf_(cc0);
      float iv1 = sigm(gb[0]+biaB[0]), fv1 = sigm(gb[1]+biaB[1]);
      float gv1 = tanhf_(gb[2]+biaB[2]), ov1 = sigm(gb[3]+biaB[3]);
      cc1 = fv1*cc1 + iv1*gv1;
      float h1 = ov1*tanhf_(cc1);
      unsigned int d0;
      asm("v_cvt_pk_bf16_f32 %0, %1, %2" : "=v"(d0) : "v"(h0), "v"(h1));
      short* dst = (short*)hb + ((size_t)t*B_ + hrow)*H_ + hoff;
      asm volatile("global_store_dword %0, %1, off sc0 sc1"
                   :: "v"(dst), "v"(d0) : "memory");
    }
    __syncthreads();                           // (E) h stores drained (gl reads done too)

    if (t < T_ - 1) {
      if (tid == 0)                            // own flag word: plain store, no RMW
        __hip_atomic_store(&bar[rg*64 + jt], (unsigned int)(t+1),
                           __ATOMIC_RELAXED, __HIP_MEMORY_SCOPE_AGENT);
      const char* gs = gseq + ((size_t)(t+1)*B_ + b0)*640;
      #pragma unroll
      for (int i = 0; i < 5; ++i) {            // prefetch seq(t+1) OFF the critical path
        int c = w*5 + i;
        dma16(gs + c*1024 + lane*16, lsc + c*1024);
      }
    }
  }
}

// ============ BN1 partial stats over (B,H) per t — order-independent, swizzle-agnostic ============
__global__ __launch_bounds__(256) void k_bn1part(
    const __hip_bfloat16* __restrict__ hb, float* __restrict__ bn1s, float* __restrict__ bn1q)
{
  const int t = blockIdx.x, ch = blockIdx.y, tid = threadIdx.x;
  const short* base = (const short*)hb + ((size_t)t*B_ + ch*64)*H_;
  float s = 0.f, q = 0.f;
  for (int i = tid; i < 64*H_/8; i += 256) {
    short8 v8 = *(const short8*)(base + (i>>6)*H_ + (i&63)*8);
    #pragma unroll
    for (int j = 0; j < 8; ++j) { float v = b2f(v8[j]); s += v; q += v*v; }
  }
  __shared__ float rs[256], rq[256];
  rs[tid] = s; rq[tid] = q;
  __syncthreads();
  for (int o = 128; o; o >>= 1) {
    if (tid < o) { rs[tid] += rs[tid+o]; rq[tid] += rq[tid+o]; }
    __syncthreads();
  }
  if (tid == 0) { bn1s[t*8 + ch] = rs[0]; bn1q[t*8 + ch] = rq[0]; }
}

// ============ head: fold BN1 + (B, T*H) @ Wl^T + bl — unswizzles hbuf slots ============
__global__ __launch_bounds__(256) void k_head(
    const __hip_bfloat16* __restrict__ hb, const float* __restrict__ bn1s,
    const float* __restrict__ bn1q, const float* __restrict__ g1,
    const float* __restrict__ be1, const float* __restrict__ Wl,
    const float* __restrict__ bl, float* __restrict__ out)
{
  const int b = blockIdx.x, tid = threadIdx.x;
  __shared__ float al1[T_], bt1[T_];
  if (tid < T_) {
    float s = 0.f, q = 0.f;
    #pragma unroll
    for (int ch = 0; ch < 8; ++ch) { s += bn1s[tid*8 + ch]; q += bn1q[tid*8 + ch]; }
    const float cnt = (float)(B_*H_);
    float mu = s / cnt, var = q / cnt - mu*mu;
    float al = g1[tid] * rsqrtf(var + EPS_);
    al1[tid] = al; bt1[tid] = be1[tid] - mu*al;
  }
  __syncthreads();
  float a0 = 0.f, a1 = 0.f, a2 = 0.f;
  const short* hbs = (const short*)hb;
  for (int p8 = tid; p8 < T_*(H_/8); p8 += 256) {
    const int t = p8 >> 6, p = p8 & 63;
    short8 v8 = *(const short8*)(hbs + ((size_t)t*B_ + b)*H_ + p*8);
    const int wi = t*H_ + ((p ^ (b & 7)) << 3);
    #pragma unroll
    for (int j = 0; j < 8; ++j) {
      float yn = b2f(v8[j])*al1[t] + bt1[t];
      a0 = fmaf(yn, Wl[wi + j],            a0);
      a1 = fmaf(yn, Wl[T_*H_ + wi + j],    a1);
      a2 = fmaf(yn, Wl[2*T_*H_ + wi + j],  a2);
    }
  }
  __shared__ float red[256];
  red[tid] = a0; __syncthreads();
  for (int o = 128; o; o >>= 1) { if (tid < o) red[tid] += red[tid+o]; __syncthreads(); }
  if (!tid) out[b*3 + 0] = red[0] + bl[0];
  __syncthreads();
  red[tid] = a1; __syncthreads();
  for (int o = 128; o; o >>= 1) { if (tid < o) red[tid] += red[tid+o]; __syncthreads(); }
  if (!tid) out[b*3 + 1] = red[0] + bl[1];
  __syncthreads();
  red[tid] = a2; __syncthreads();
  for (int o = 128; o; o >>= 1) { if (tid < o) red[tid] += red[tid+o]; __syncthreads(); }
  if (!tid) out[b*3 + 2] = red[0] + bl[2];
}

extern "C" void kernel_launch(void* const* d_in, const int* in_sizes, int n_in,
                              void* d_out, int out_size, void* d_ws, size_t ws_size,
                              hipStream_t stream)
{
  (void)in_sizes; (void)n_in; (void)out_size;
  const float* x   = (const float*)d_in[0];
  const int* esrc  = (const int*)d_in[1];
  const int* edst  = (const int*)d_in[2];
  const float* ew  = (const float*)d_in[3];
  const float* Wc  = (const float*)d_in[4];
  const float* bc  = (const float*)d_in[5];
  const float* bng = (const float*)d_in[6];
  const float* bnb = (const float*)d_in[7];
  const float* Wih = (const float*)d_in[8];
  const float* Whh = (const float*)d_in[9];
  const float* bih = (const float*)d_in[10];
  const float* bhh = (const float*)d_in[11];
  const float* g1  = (const float*)d_in[12];
  const float* be1 = (const float*)d_in[13];
  const float* Wl  = (const float*)d_in[14];
  const float* bl  = (const float*)d_in[15];
  float* out = (float*)d_out;

  char* ws = (char*)d_ws;
  size_t off = 0;
  auto alloc = [&](size_t bytes) {
    void* p = ws + off;
    off += (bytes + 255) & ~(size_t)255;
    return p;
  };
  float* cheb = (float*)alloc(sizeof(float)*(size_t)T_*B_*NF_);
  float* bps  = (float*)alloc(sizeof(float)*T_*F_*B_);
  float* bpq  = (float*)alloc(sizeof(float)*T_*F_*B_);
  float* alpha= (float*)alloc(sizeof(float)*T_*F_);
  float* bet  = (float*)alloc(sizeof(float)*T_*F_);
  __hip_bfloat16* seqb = (__hip_bfloat16*)alloc(sizeof(__hip_bfloat16)*(size_t)T_*B_*SEQP);
  __hip_bfloat16* Wcat = (__hip_bfloat16*)alloc(sizeof(__hip_bfloat16)*(size_t)G4*KPAD);
  float* biasr = (float*)alloc(sizeof(float)*G4);
  __hip_bfloat16* hbuf = (__hip_bfloat16*)alloc(sizeof(__hip_bfloat16)*(size_t)T_*B_*H_);
  float* bn1s = (float*)alloc(sizeof(float)*T_*8);
  float* bn1q = (float*)alloc(sizeof(float)*T_*8);
  unsigned int* bar = (unsigned int*)alloc(sizeof(unsigned int)*16*64);
  if (ws_size < off) return;   // ~76 MB — within proven budget

  (void)hipMemsetAsync(bar, 0, sizeof(unsigned int)*16*64, stream);

  k_cheb<<<dim3(B_, T_/TC), 512, 0, stream>>>(x, esrc, edst, ew, Wc, bc, cheb, bps, bpq);
  k_bnfin<<<T_*F_, 64, 0, stream>>>(bps, bpq, bng, bnb, alpha, bet);
  k_seq<<<(T_*B_*SEQP)/256, 256, 0, stream>>>(cheb, alpha, bet, seqb);
  k_prep<<<G4, 256, 0, stream>>>(Wih, Whh, bih, bhh, Wcat, biasr);

  k_lstm<<<512, 256, 0, stream>>>(seqb, Wcat, biasr, hbuf, bar);

  k_bn1part<<<dim3(T_, 8), 256, 0, stream>>>(hbuf, bn1s, bn1q);
  k_head<<<B_, 256, 0, stream>>>(hbuf, bn1s, bn1q, g1, be1, Wl, bl, out);
}

// Round 12
// 258.299 us; speedup vs baseline: 9.3128x; 1.0642x over previous
//
#include <hip/hip_runtime.h>
#include <hip/hip_bf16.h>
#include <cstdint>

#define B_ 512
#define T_ 48
#define N_ 62
#define F_ 5
#define E_ 496
#define H_ 512
#define NF_ 310      // N*F
#define SEQP 320     // padded seq row (310 -> 320)
#define KPAD 832     // 320 + 512
#define G4 2048      // 4*H
#define EPS_ 1e-5f
#define TC 12        // t-steps per cheb block (4 chunks)
#define LSTR 72      // LDS row stride in shorts

typedef __attribute__((ext_vector_type(8))) short short8;
typedef __attribute__((ext_vector_type(4))) short s16x4;
typedef __attribute__((ext_vector_type(4))) float f32x4;

__device__ __forceinline__ float sigm(float x)  { return 1.f / (1.f + __expf(-x)); }
__device__ __forceinline__ float tanhf_(float x){ return 2.f / (1.f + __expf(-2.f*x)) - 1.f; }

__device__ __forceinline__ short f2b(float v) {   // f32 -> bf16 bits, RN-even
  unsigned int u = __builtin_bit_cast(unsigned int, v);
  unsigned int r = (u + 0x7fffu + ((u >> 16) & 1u)) >> 16;
  return (short)r;
}
__device__ __forceinline__ float b2f(short s) {
  unsigned int u = ((unsigned int)(unsigned short)s) << 16;
  return __builtin_bit_cast(float, u);
}

__device__ __forceinline__ void dma16(const void* g, void* l) {
  __builtin_amdgcn_global_load_lds(
      (const __attribute__((address_space(1))) unsigned int*)g,
      (__attribute__((address_space(3))) unsigned int*)l, 16, 0, 0);
}

// ============ ChebConv K=3 via MFMA + BN partial stats; block = (graph, 12-t chunk) ============
__global__ __launch_bounds__(512) void k_cheb(
    const float* __restrict__ x, const int* __restrict__ esrc, const int* __restrict__ edst,
    const float* __restrict__ ew, const float* __restrict__ Wc, const float* __restrict__ bc,
    float* __restrict__ cheb, float* __restrict__ bps, float* __restrict__ bpq)
{
  __shared__ __align__(16) short SH[4*64*LSTR];
  __shared__ float dinv[N_];
  short* Lb  = SH;
  short* Xt  = SH + 64*LSTR;
  short* T1t = SH + 2*64*LSTR;
  short* T2t = SH + 3*64*LSTR;
  float* Af  = (float*)T1t;

  const int tid = threadIdx.x;
  const int b = blockIdx.x;
  const int t0 = blockIdx.y * TC;

  for (int i = tid; i < 2*64*LSTR; i += 512) SH[i] = 0;
  for (int i = tid; i < N_*N_;     i += 512) Af[i] = 0.f;
  __syncthreads();

  for (int e = tid; e < E_; e += 512)
    atomicAdd(&Af[edst[b*E_ + e]*N_ + esrc[b*E_ + e]], ew[b*E_ + e]);
  for (int i = tid; i < TC*NF_; i += 512) {
    int tl = i / NF_, nf = i - tl*NF_;
    float v = x[((size_t)b*T_ + t0 + tl)*NF_ + nf];
    int n = nf / F_, f = nf - n*F_;
    Xt[(tl*F_ + f)*LSTR + n] = f2b(v);
  }
  __syncthreads();

  if (tid < N_) {
    float s = 0.f;
    for (int m = 0; m < N_; ++m) s += Af[tid*N_ + m];
    dinv[tid] = (s > 0.f) ? rsqrtf(s) : 0.f;
  }
  __syncthreads();
  for (int i = tid; i < N_*N_; i += 512) {
    int n = i / N_, m = i - n*N_;
    Lb[n*LSTR + m] = f2b(-dinv[n] * Af[i] * dinv[m]);
  }
  __syncthreads();

  const int w = tid >> 6, lane = tid & 63, l16 = lane & 15, lhi = lane >> 4;
  const int mt = w >> 1;
  const int nt = (w & 1) * 2;

  {
    f32x4 acc0 = {0.f,0.f,0.f,0.f}, acc1 = acc0;
    #pragma unroll
    for (int kc = 0; kc < 2; ++kc) {
      short8 a  = *(const short8*)(Lb + (mt*16 + l16)*LSTR + kc*32 + lhi*8);
      short8 b0 = *(const short8*)(Xt + ((nt  )*16 + l16)*LSTR + kc*32 + lhi*8);
      short8 b1 = *(const short8*)(Xt + ((nt+1)*16 + l16)*LSTR + kc*32 + lhi*8);
      acc0 = __builtin_amdgcn_mfma_f32_16x16x32_bf16(a, b0, acc0, 0, 0, 0);
      acc1 = __builtin_amdgcn_mfma_f32_16x16x32_bf16(a, b1, acc1, 0, 0, 0);
    }
    #pragma unroll
    for (int i = 0; i < 2; ++i) {
      f32x4 acc = i ? acc1 : acc0;
      int c = (nt+i)*16 + l16, n = mt*16 + lhi*4;
      s16x4 pk;
      #pragma unroll
      for (int r = 0; r < 4; ++r) pk[r] = f2b(acc[r]);
      *(s16x4*)(T1t + c*LSTR + n) = pk;
    }
  }
  __syncthreads();

  {
    f32x4 acc0 = {0.f,0.f,0.f,0.f}, acc1 = acc0;
    #pragma unroll
    for (int kc = 0; kc < 2; ++kc) {
      short8 a  = *(const short8*)(Lb + (mt*16 + l16)*LSTR + kc*32 + lhi*8);
      short8 b0 = *(const short8*)(T1t + ((nt  )*16 + l16)*LSTR + kc*32 + lhi*8);
      short8 b1 = *(const short8*)(T1t + ((nt+1)*16 + l16)*LSTR + kc*32 + lhi*8);
      acc0 = __builtin_amdgcn_mfma_f32_16x16x32_bf16(a, b0, acc0, 0, 0, 0);
      acc1 = __builtin_amdgcn_mfma_f32_16x16x32_bf16(a, b1, acc1, 0, 0, 0);
    }
    #pragma unroll
    for (int i = 0; i < 2; ++i) {
      f32x4 acc = i ? acc1 : acc0;
      int c = (nt+i)*16 + l16, n = mt*16 + lhi*4;
      s16x4 xv = *(const s16x4*)(Xt + c*LSTR + n);
      s16x4 pk;
      #pragma unroll
      for (int r = 0; r < 4; ++r) pk[r] = f2b(2.f*acc[r] - b2f(xv[r]));
      *(s16x4*)(T2t + c*LSTR + n) = pk;
    }
  }
  __syncthreads();

  const int pair = tid >> 2, q = tid & 3;
  if (pair < TC*F_) {
    const int tl = pair / F_, g = pair - (pair/F_)*F_;
    const int t = t0 + tl;
    float w0[5], w1[5], w2[5];
    #pragma unroll
    for (int ff = 0; ff < 5; ++ff) {
      w0[ff] = Wc[t*75 +      ff*5 + g];
      w1[ff] = Wc[t*75 + 25 + ff*5 + g];
      w2[ff] = Wc[t*75 + 50 + ff*5 + g];
    }
    const float bias = bc[t*F_ + g];
    float ss = 0.f, qq = 0.f;
    float* chout = cheb + ((size_t)t*B_ + b)*NF_;
    #pragma unroll
    for (int grp = 0; grp < 4; ++grp) {
      int n4 = grp*16 + q*4;
      float o[4] = {bias, bias, bias, bias};
      #pragma unroll
      for (int ff = 0; ff < 5; ++ff) {
        int c = tl*F_ + ff;
        s16x4 xv = *(const s16x4*)(Xt  + c*LSTR + n4);
        s16x4 v1 = *(const s16x4*)(T1t + c*LSTR + n4);
        s16x4 v2 = *(const s16x4*)(T2t + c*LSTR + n4);
        #pragma unroll
        for (int i = 0; i < 4; ++i)
          o[i] += b2f(xv[i])*w0[ff] + b2f(v1[i])*w1[ff] + b2f(v2[i])*w2[ff];
      }
      #pragma unroll
      for (int i = 0; i < 4; ++i) {
        int n = n4 + i;
        if (n < N_) { chout[n*F_ + g] = o[i]; ss += o[i]; qq += o[i]*o[i]; }
      }
    }
    ss += __shfl_down(ss, 2, 4); ss += __shfl_down(ss, 1, 4);
    qq += __shfl_down(qq, 2, 4); qq += __shfl_down(qq, 1, 4);
    if (q == 0) { bps[(t*F_ + g)*B_ + b] = ss; bpq[(t*F_ + g)*B_ + b] = qq; }
  }
}

// ============ finalize BN scale/shift per (t,f) ============
__global__ __launch_bounds__(64) void k_bnfin(
    const float* __restrict__ bps, const float* __restrict__ bpq,
    const float* __restrict__ bng, const float* __restrict__ bnb,
    float* __restrict__ alpha, float* __restrict__ bet)
{
  const int tf = blockIdx.x;
  const int lane = threadIdx.x;
  float s = 0.f, q = 0.f;
  for (int i = lane; i < B_; i += 64) { s += bps[tf*B_ + i]; q += bpq[tf*B_ + i]; }
  #pragma unroll
  for (int off = 32; off; off >>= 1) { s += __shfl_down(s, off); q += __shfl_down(q, off); }
  if (lane == 0) {
    const float cnt = (float)(B_*N_);
    float mu = s / cnt;
    float var = q / cnt - mu*mu;
    float al = bng[tf] * rsqrtf(var + EPS_);
    alpha[tf] = al;
    bet[tf] = bnb[tf] - mu*al;
  }
}

// ============ BN apply + pack to bf16 PRE-SWIZZLED sequence [t][b][320] ============
__global__ __launch_bounds__(256) void k_seq(
    const float* __restrict__ cheb, const float* __restrict__ alpha, const float* __restrict__ bet,
    __hip_bfloat16* __restrict__ seqb)
{
  int idx = blockIdx.x*256 + threadIdx.x;     // T*B*320
  int kp = idx % SEQP;                        // physical position
  int tb = idx / SEQP;
  int b = tb & (B_-1), t = tb >> 9;
  int sl = (kp >> 3) ^ (b & 7);               // logical slot
  int kl = sl*8 + (kp & 7);                   // logical element
  float v = 0.f;
  if (kl < NF_) v = cheb[(size_t)tb*NF_ + kl] * alpha[t*F_ + (kl % F_)] + bet[t*F_ + (kl % F_)];
  seqb[idx] = __float2bfloat16(v);
}

// ============ weight prep: gate-interleaved rows j' = jh*4 + gate; K = [seq-logical|pad|h] ============
__global__ __launch_bounds__(256) void k_prep(
    const float* __restrict__ Wih, const float* __restrict__ Whh,
    const float* __restrict__ bih, const float* __restrict__ bhh,
    __hip_bfloat16* __restrict__ Wcat, float* __restrict__ biasr)
{
  const int jp = blockIdx.x;
  const int g = jp & 3, jh = jp >> 2;
  const int jo = g*H_ + jh;
  for (int k = threadIdx.x; k < KPAD; k += 256) {
    float v = 0.f;
    if (k < NF_) v = Wih[(size_t)jo*NF_ + k];
    else if (k >= SEQP) v = Whh[(size_t)jo*H_ + (k - SEQP)];
    Wcat[(size_t)jp*KPAD + k] = __float2bfloat16(v);
  }
  if (threadIdx.x == 0) biasr[jp] = bih[jo] + bhh[jo];
}

// ============ persistent LSTM v7: 512-thr blocks, 16-block groups (halved fan-out) ============
// 256 blocks (1/CU) x 512 thr (8 waves, 2/SIMD). Block (rg=bid&15, jt=bid>>4):
// 32 b-rows x 128 j'-cols. Groups of 16 blocks exchange h via write-once swizzled
// hbuf (sc0 sc1 -> LLC) + per-producer flag words; 16-lane parallel poll.
#define WOP(M)  M(0) M(1) M(2) M(3) M(4) M(5) M(6) M(7) M(8) M(9) M(10) M(11) M(12) M(13) \
                M(14) M(15) M(16) M(17) M(18) M(19) M(20) M(21) M(22) M(23) M(24) M(25)
#define WSEQ(M) M(0) M(1) M(2) M(3) M(4) M(5) M(6) M(7) M(8) M(9)
#define WHP(M)  M(10) M(11) M(12) M(13) M(14) M(15) M(16) M(17) M(18) M(19) M(20) M(21) \
                M(22) M(23) M(24) M(25)

#define DECLW(i) short8 wv##i;
#define LOADW(i) wv##i = *(const short8*)(wp + (i)*32); \
                 asm volatile("" : "+v"(wv##i));
#define MFS(i) { const int ph = (((i)*4 + lhi) ^ key)*8; \
                 short8 x0 = *(const short8*)(lseq + rs0*SEQP + ph); \
                 short8 x1 = *(const short8*)(lseq + rs1*SEQP + ph); \
                 a0 = __builtin_amdgcn_mfma_f32_16x16x32_bf16(x0, wv##i, a0, 0, 0, 0); \
                 a1 = __builtin_amdgcn_mfma_f32_16x16x32_bf16(x1, wv##i, a1, 0, 0, 0); }
#define MFH(i) { const int ph = ((((i)-10)*4 + lhi) ^ key)*8; \
                 short8 x0 = *(const short8*)(lh + rs0*H_ + ph); \
                 short8 x1 = *(const short8*)(lh + rs1*H_ + ph); \
                 a0 = __builtin_amdgcn_mfma_f32_16x16x32_bf16(x0, wv##i, a0, 0, 0, 0); \
                 a1 = __builtin_amdgcn_mfma_f32_16x16x32_bf16(x1, wv##i, a1, 0, 0, 0); }

__global__ __launch_bounds__(512, 1) void k_lstm(
    const __hip_bfloat16* __restrict__ seqb,   // (T, B, 320) bf16, slot-swizzled
    const __hip_bfloat16* __restrict__ Wcat,   // (2048, 832) gate-interleaved
    const float* __restrict__ biasr,           // (2048)
    __hip_bfloat16* __restrict__ hb,           // (T, B, 512) bf16, slot-swizzled, write-once
    unsigned int* __restrict__ bar)            // (16*64) zeroed, rg-major flag words
{
  __shared__ __align__(16) short lh[32*H_];    // 32 KB: h panel
  __shared__ __align__(16) short lseq[32*SEQP];// 20 KB: seq panel
  __shared__ __align__(16) float gl[32][132];  // 16.5 KB: gate tile

  const int tid = threadIdx.x;
  const int bid = blockIdx.x;
  const int rg = bid & 15, jt = bid >> 4;      // jt in 0..15
  const int b0 = rg*32, j0 = jt*128;
  const int w = tid >> 6, lane = tid & 63, l16 = lane & 15, lhi = lane >> 4;
  const int key = l16 & 7;
  const int rs0 = l16, rs1 = l16 + 16;

  // ---- pin this wave's 26 weight fragments (col-tile = j0 + w*16) ----
  const short* wp = (const short*)Wcat + (size_t)(j0 + w*16 + l16)*KPAD + lhi*8;
  WOP(DECLW)
  WOP(LOADW)

  // cell mapping: 32 rows x 32 units; thread -> (crow = tid>>4, u2 = tid&15, 2 units)
  const int crow = tid >> 4, u2 = tid & 15;
  const int hrow = b0 + crow;
  float cc0 = 0.f, cc1 = 0.f;
  f32x4 biaA = *(const f32x4*)(biasr + j0 + u2*8 + 0);
  f32x4 biaB = *(const f32x4*)(biasr + j0 + u2*8 + 4);
  const int hslot = (jt*4 + (u2 >> 2)) ^ (hrow & 7);
  const int hoff = hslot*8 + (u2 & 3)*2;

  const char* gseq = (const char*)seqb;
  const char* ghb  = (const char*)hb;
  char* lsc = (char*)lseq;
  char* lhc = (char*)lh;

  // prologue: stage seq(0): 20KB contiguous
  {
    const char* gs = gseq + ((size_t)b0)*640;
    #pragma unroll
    for (int i = 0; i < 3; ++i) {
      int c = w + i*8;
      if (c < 20) dma16(gs + c*1024 + lane*16, lsc + c*1024);
    }
  }

  #pragma unroll 1
  for (int t = 0; t < T_; ++t) {
    // ---- wait for all 16 producers' flags >= t (parallel 16-lane probe) ----
    if (t > 0 && w == 0) {
      for (;;) {
        unsigned int v = 0xFFFFFFFFu;
        if (lane < 16)
          v = __hip_atomic_load(&bar[rg*64 + lane], __ATOMIC_RELAXED,
                                __HIP_MEMORY_SCOPE_AGENT);
        if (__all(v >= (unsigned int)t)) break;
        __builtin_amdgcn_s_sleep(1);
      }
    }
    __syncthreads();                           // (A) seq(t) staged; flags seen; prefetch drained

    if (t > 0) {                               // stage h(t-1): 32 x 1KB rows, 4 dma16/wave
      const char* gh = ghb + ((size_t)(t-1)*B_ + b0)*1024;
      #pragma unroll
      for (int i = 0; i < 4; ++i) {
        int c = w*4 + i;
        dma16(gh + c*1024 + lane*16, lhc + c*1024);
      }
    }

    // seq-part MFMAs (overlap h DMA)
    f32x4 a0 = {0.f,0.f,0.f,0.f}, a1 = a0;
    WSEQ(MFS)

    if (t > 0) {
      __syncthreads();                         // (B) h DMA drained (all waves)
      WHP(MFH)
    }

    #pragma unroll
    for (int r = 0; r < 4; ++r) {
      gl[     lhi*4 + r][w*16 + l16] = a0[r];
      gl[16 + lhi*4 + r][w*16 + l16] = a1[r];
    }
    __syncthreads();                           // (D) gl visible

    // cell update: 2 hidden units per thread
    {
      f32x4 ga = *(const f32x4*)(&gl[crow][u2*8 + 0]);
      f32x4 gb = *(const f32x4*)(&gl[crow][u2*8 + 4]);
      float iv0 = sigm(ga[0]+biaA[0]), fv0 = sigm(ga[1]+biaA[1]);
      float gv0 = tanhf_(ga[2]+biaA[2]), ov0 = sigm(ga[3]+biaA[3]);
      cc0 = fv0*cc0 + iv0*gv0;
      float h0 = ov0*tanhf_(cc0);
      float iv1 = sigm(gb[0]+biaB[0]), fv1 = sigm(gb[1]+biaB[1]);
      float gv1 = tanhf_(gb[2]+biaB[2]), ov1 = sigm(gb[3]+biaB[3]);
      cc1 = fv1*cc1 + iv1*gv1;
      float h1 = ov1*tanhf_(cc1);
      unsigned int d0;
      asm("v_cvt_pk_bf16_f32 %0, %1, %2" : "=v"(d0) : "v"(h0), "v"(h1));
      short* dst = (short*)hb + ((size_t)t*B_ + hrow)*H_ + hoff;
      asm volatile("global_store_dword %0, %1, off sc0 sc1"
                   :: "v"(dst), "v"(d0) : "memory");
    }
    __syncthreads();                           // (E) h stores drained (gl reads done too)

    if (t < T_ - 1) {
      if (tid == 0)                            // own flag word: plain store, no RMW
        __hip_atomic_store(&bar[rg*64 + jt], (unsigned int)(t+1),
                           __ATOMIC_RELAXED, __HIP_MEMORY_SCOPE_AGENT);
      const char* gs = gseq + ((size_t)(t+1)*B_ + b0)*640;
      #pragma unroll
      for (int i = 0; i < 3; ++i) {            // prefetch seq(t+1) OFF the critical path
        int c = w + i*8;
        if (c < 20) dma16(gs + c*1024 + lane*16, lsc + c*1024);
      }
    }
  }
}

// ============ BN1 partial stats over (B,H) per t — order-independent, swizzle-agnostic ============
__global__ __launch_bounds__(256) void k_bn1part(
    const __hip_bfloat16* __restrict__ hb, float* __restrict__ bn1s, float* __restrict__ bn1q)
{
  const int t = blockIdx.x, ch = blockIdx.y, tid = threadIdx.x;
  const short* base = (const short*)hb + ((size_t)t*B_ + ch*64)*H_;
  float s = 0.f, q = 0.f;
  for (int i = tid; i < 64*H_/8; i += 256) {
    short8 v8 = *(const short8*)(base + (i>>6)*H_ + (i&63)*8);
    #pragma unroll
    for (int j = 0; j < 8; ++j) { float v = b2f(v8[j]); s += v; q += v*v; }
  }
  __shared__ float rs[256], rq[256];
  rs[tid] = s; rq[tid] = q;
  __syncthreads();
  for (int o = 128; o; o >>= 1) {
    if (tid < o) { rs[tid] += rs[tid+o]; rq[tid] += rq[tid+o]; }
    __syncthreads();
  }
  if (tid == 0) { bn1s[t*8 + ch] = rs[0]; bn1q[t*8 + ch] = rq[0]; }
}

// ============ head: fold BN1 + (B, T*H) @ Wl^T + bl — unswizzles hbuf slots ============
__global__ __launch_bounds__(256) void k_head(
    const __hip_bfloat16* __restrict__ hb, const float* __restrict__ bn1s,
    const float* __restrict__ bn1q, const float* __restrict__ g1,
    const float* __restrict__ be1, const float* __restrict__ Wl,
    const float* __restrict__ bl, float* __restrict__ out)
{
  const int b = blockIdx.x, tid = threadIdx.x;
  __shared__ float al1[T_], bt1[T_];
  if (tid < T_) {
    float s = 0.f, q = 0.f;
    #pragma unroll
    for (int ch = 0; ch < 8; ++ch) { s += bn1s[tid*8 + ch]; q += bn1q[tid*8 + ch]; }
    const float cnt = (float)(B_*H_);
    float mu = s / cnt, var = q / cnt - mu*mu;
    float al = g1[tid] * rsqrtf(var + EPS_);
    al1[tid] = al; bt1[tid] = be1[tid] - mu*al;
  }
  __syncthreads();
  float a0 = 0.f, a1 = 0.f, a2 = 0.f;
  const short* hbs = (const short*)hb;
  for (int p8 = tid; p8 < T_*(H_/8); p8 += 256) {
    const int t = p8 >> 6, p = p8 & 63;
    short8 v8 = *(const short8*)(hbs + ((size_t)t*B_ + b)*H_ + p*8);
    const int wi = t*H_ + ((p ^ (b & 7)) << 3);
    #pragma unroll
    for (int j = 0; j < 8; ++j) {
      float yn = b2f(v8[j])*al1[t] + bt1[t];
      a0 = fmaf(yn, Wl[wi + j],            a0);
      a1 = fmaf(yn, Wl[T_*H_ + wi + j],    a1);
      a2 = fmaf(yn, Wl[2*T_*H_ + wi + j],  a2);
    }
  }
  __shared__ float red[256];
  red[tid] = a0; __syncthreads();
  for (int o = 128; o; o >>= 1) { if (tid < o) red[tid] += red[tid+o]; __syncthreads(); }
  if (!tid) out[b*3 + 0] = red[0] + bl[0];
  __syncthreads();
  red[tid] = a1; __syncthreads();
  for (int o = 128; o; o >>= 1) { if (tid < o) red[tid] += red[tid+o]; __syncthreads(); }
  if (!tid) out[b*3 + 1] = red[0] + bl[1];
  __syncthreads();
  red[tid] = a2; __syncthreads();
  for (int o = 128; o; o >>= 1) { if (tid < o) red[tid] += red[tid+o]; __syncthreads(); }
  if (!tid) out[b*3 + 2] = red[0] + bl[2];
}

extern "C" void kernel_launch(void* const* d_in, const int* in_sizes, int n_in,
                              void* d_out, int out_size, void* d_ws, size_t ws_size,
                              hipStream_t stream)
{
  (void)in_sizes; (void)n_in; (void)out_size;
  const float* x   = (const float*)d_in[0];
  const int* esrc  = (const int*)d_in[1];
  const int* edst  = (const int*)d_in[2];
  const float* ew  = (const float*)d_in[3];
  const float* Wc  = (const float*)d_in[4];
  const float* bc  = (const float*)d_in[5];
  const float* bng = (const float*)d_in[6];
  const float* bnb = (const float*)d_in[7];
  const float* Wih = (const float*)d_in[8];
  const float* Whh = (const float*)d_in[9];
  const float* bih = (const float*)d_in[10];
  const float* bhh = (const float*)d_in[11];
  const float* g1  = (const float*)d_in[12];
  const float* be1 = (const float*)d_in[13];
  const float* Wl  = (const float*)d_in[14];
  const float* bl  = (const float*)d_in[15];
  float* out = (float*)d_out;

  char* ws = (char*)d_ws;
  size_t off = 0;
  auto alloc = [&](size_t bytes) {
    void* p = ws + off;
    off += (bytes + 255) & ~(size_t)255;
    return p;
  };
  float* cheb = (float*)alloc(sizeof(float)*(size_t)T_*B_*NF_);
  float* bps  = (float*)alloc(sizeof(float)*T_*F_*B_);
  float* bpq  = (float*)alloc(sizeof(float)*T_*F_*B_);
  float* alpha= (float*)alloc(sizeof(float)*T_*F_);
  float* bet  = (float*)alloc(sizeof(float)*T_*F_);
  __hip_bfloat16* seqb = (__hip_bfloat16*)alloc(sizeof(__hip_bfloat16)*(size_t)T_*B_*SEQP);
  __hip_bfloat16* Wcat = (__hip_bfloat16*)alloc(sizeof(__hip_bfloat16)*(size_t)G4*KPAD);
  float* biasr = (float*)alloc(sizeof(float)*G4);
  __hip_bfloat16* hbuf = (__hip_bfloat16*)alloc(sizeof(__hip_bfloat16)*(size_t)T_*B_*H_);
  float* bn1s = (float*)alloc(sizeof(float)*T_*8);
  float* bn1q = (float*)alloc(sizeof(float)*T_*8);
  unsigned int* bar = (unsigned int*)alloc(sizeof(unsigned int)*16*64);
  if (ws_size < off) return;   // ~76 MB — within proven budget

  (void)hipMemsetAsync(bar, 0, sizeof(unsigned int)*16*64, stream);

  k_cheb<<<dim3(B_, T_/TC), 512, 0, stream>>>(x, esrc, edst, ew, Wc, bc, cheb, bps, bpq);
  k_bnfin<<<T_*F_, 64, 0, stream>>>(bps, bpq, bng, bnb, alpha, bet);
  k_seq<<<(T_*B_*SEQP)/256, 256, 0, stream>>>(cheb, alpha, bet, seqb);
  k_prep<<<G4, 256, 0, stream>>>(Wih, Whh, bih, bhh, Wcat, biasr);

  k_lstm<<<256, 512, 0, stream>>>(seqb, Wcat, biasr, hbuf, bar);

  k_bn1part<<<dim3(T_, 8), 256, 0, stream>>>(hbuf, bn1s, bn1q);
  k_head<<<B_, 256, 0, stream>>>(hbuf, bn1s, bn1q, g1, be1, Wl, bl, out);
}